// Round 5
// baseline (977.635 us; speedup 1.0000x reference)
//
#include <hip/hip_runtime.h>
#include <hip/hip_bf16.h>

// Problem constants
#define D_MODEL 256
#define D_INNER 512
#define NHEADS 8
#define HEADDIM 64
#define MDIST 16
#define BB 4
#define LL 2048
#define QQ 300
#define QP 320          // padded Q
#define NSEG 16
#define SEGLEN 128      // LL / NSEG

typedef unsigned short ushort_t;
typedef __attribute__((ext_vector_type(8))) short bf16x8;
typedef __attribute__((ext_vector_type(4))) float f32x4;
typedef __attribute__((ext_vector_type(2))) float f32x2;

__device__ __forceinline__ void bf16_split(float v, ushort_t& hi, ushort_t& lo) {
    __hip_bfloat16 h = __float2bfloat16(v);
    float hf = __bfloat162float(h);
    __hip_bfloat16 l = __float2bfloat16(v - hf);
    hi = *(ushort_t*)&h;
    lo = *(ushort_t*)&l;
}

__device__ __forceinline__ f32x2 shfl_xor2(f32x2 v, int m) {
    f32x2 r;
    r.x = __shfl_xor(v.x, m, 64);
    r.y = __shfl_xor(v.y, m, 64);
    return r;
}

// DPP cross-lane move (VALU pipe, NOT the shared DS pipe).
// quad_perm 0xB1 = xor1, 0x4E = xor2, 0x128 = row_ror:8 (xor8 within row of 16).
template<int CTRL>
__device__ __forceinline__ f32x2 dpp2(f32x2 v) {
    f32x2 r;
    r.x = __int_as_float(__builtin_amdgcn_update_dpp(0, __float_as_int(v.x), CTRL, 0xF, 0xF, true));
    r.y = __int_as_float(__builtin_amdgcn_update_dpp(0, __float_as_int(v.y), CTRL, 0xF, 0xF, true));
    return r;
}
// ds_swizzle xor patterns: 0x101F = xor4, 0x401F = xor16
template<int OFF>
__device__ __forceinline__ f32x2 swz2(f32x2 v) {
    f32x2 r;
    r.x = __int_as_float(__builtin_amdgcn_ds_swizzle(__float_as_int(v.x), OFF));
    r.y = __int_as_float(__builtin_amdgcn_ds_swizzle(__float_as_int(v.y), OFF));
    return r;
}

// Packed fp32 math (VOP3P, gfx90a+/CDNA). Forced via asm: R4's VALUBusy
// implies the compiler scalarized f32x2 arithmetic (2x inst count).
__device__ __forceinline__ f32x2 pk_mul(f32x2 a, f32x2 b) {
    f32x2 d;
    asm("v_pk_mul_f32 %0, %1, %2" : "=v"(d) : "v"(a), "v"(b));
    return d;
}
__device__ __forceinline__ f32x2 pk_fma(f32x2 a, f32x2 b, f32x2 c) {
    f32x2 d;
    asm("v_pk_fma_f32 %0, %1, %2, %3" : "=v"(d) : "v"(a), "v"(b), "v"(c));
    return d;
}

// ---------------------------------------------------------------------------
// Split fp32 -> bf16 hi + bf16 lo (residual). C = Ah*Bh + Ah*Bl + Al*Bh gives
// ~fp32 accuracy (missing Al*Bl term ~2^-18 relative).
// ---------------------------------------------------------------------------
__global__ __launch_bounds__(256) void c_split(const float* __restrict__ in,
                                               ushort_t* __restrict__ hi,
                                               ushort_t* __restrict__ lo, int n) {
    int i = blockIdx.x * 256 + threadIdx.x;
    if (i >= n) return;
    ushort_t h, l;
    bf16_split(in[i], h, l);
    hi[i] = h;
    lo[i] = l;
}

// ---------------------------------------------------------------------------
// Split-bf16 MFMA GEMM: C[M,N] = A[M,K] * B[N,K]^T (NT), fp32 out.
// ---------------------------------------------------------------------------
__global__ __launch_bounds__(256) void gemm_bf16s(const ushort_t* __restrict__ Ah,
                                                  const ushort_t* __restrict__ Al,
                                                  const ushort_t* __restrict__ Bh,
                                                  const ushort_t* __restrict__ Bl,
                                                  float* __restrict__ C,
                                                  int M, int N, int K) {
    int w = threadIdx.x >> 6, lane = threadIdx.x & 63;
    int n0 = blockIdx.x * 64;
    int m0 = blockIdx.y * 128 + w * 32;
    int lm = lane & 15, lk = (lane >> 4) * 8;
    f32x4 acc[2][4];
#pragma unroll
    for (int i = 0; i < 2; i++)
#pragma unroll
        for (int j = 0; j < 4; j++) acc[i][j] = {0.f, 0.f, 0.f, 0.f};

    for (int k0 = 0; k0 < K; k0 += 32) {
        bf16x8 ah[2], al[2], bh[4], blo[4];
#pragma unroll
        for (int mf = 0; mf < 2; mf++) {
            int row = m0 + mf * 16 + lm;
            if (row >= M) row = M - 1;            // safe clamp; epilogue guards
            size_t off = (size_t)row * K + k0 + lk;
            ah[mf] = *(const bf16x8*)(Ah + off);
            al[mf] = *(const bf16x8*)(Al + off);
        }
#pragma unroll
        for (int nf = 0; nf < 4; nf++) {
            int col = n0 + nf * 16 + lm;
            size_t off = (size_t)col * K + k0 + lk;
            bh[nf]  = *(const bf16x8*)(Bh + off);
            blo[nf] = *(const bf16x8*)(Bl + off);
        }
#pragma unroll
        for (int mf = 0; mf < 2; mf++)
#pragma unroll
            for (int nf = 0; nf < 4; nf++) {
                acc[mf][nf] = __builtin_amdgcn_mfma_f32_16x16x32_bf16(ah[mf], bh[nf],  acc[mf][nf], 0, 0, 0);
                acc[mf][nf] = __builtin_amdgcn_mfma_f32_16x16x32_bf16(ah[mf], blo[nf], acc[mf][nf], 0, 0, 0);
                acc[mf][nf] = __builtin_amdgcn_mfma_f32_16x16x32_bf16(al[mf], bh[nf],  acc[mf][nf], 0, 0, 0);
            }
    }
#pragma unroll
    for (int mf = 0; mf < 2; mf++)
#pragma unroll
        for (int nf = 0; nf < 4; nf++)
#pragma unroll
            for (int r = 0; r < 4; r++) {
                int m = m0 + mf * 16 + (lane >> 4) * 4 + r;
                if (m < M) C[(size_t)m * N + n0 + nf * 16 + lm] = acc[mf][nf][r];
            }
}

// ---------------------------------------------------------------------------
// K1b: fp32 bias columns (rows 1024..1033 of W_key) — precision-critical.
// ---------------------------------------------------------------------------
__global__ __launch_bounds__(256) void k1b_bias(const float* __restrict__ in_key,
                                                const float* __restrict__ W_key,
                                                float* __restrict__ bias10) {
    int w = threadIdx.x >> 6, lane = threadIdx.x & 63;
    int row = blockIdx.x * 4 + w;
    float4 a = *(const float4*)(in_key + (size_t)row * 256 + lane * 4);
#pragma unroll
    for (int c = 0; c < 10; c++) {
        float4 b = *(const float4*)(W_key + (size_t)(1024 + c) * 256 + lane * 4);
        float t = a.x * b.x + a.y * b.y + a.z * b.z + a.w * b.w;
#pragma unroll
        for (int o = 32; o > 0; o >>= 1) t += __shfl_down(t, o, 64);
        if (lane == 0) bias10[row * 10 + c] = t;
    }
}

// ---------------------------------------------------------------------------
// K2: dist (B,L,Q,16) -> dAB (B,L,H,QP,{dA,dtB}) packed float2, Cm (B,L,QP).
// ---------------------------------------------------------------------------
__global__ __launch_bounds__(256) void k2_dist(const float* __restrict__ dist,
                                               const float* __restrict__ bias10,
                                               const float* __restrict__ W_bc,
                                               const float* __restrict__ W_dt,
                                               const float* __restrict__ dt_bias,
                                               const float* __restrict__ A_log,
                                               float* __restrict__ dAB,
                                               float* __restrict__ Cm) {
    __shared__ float sWbc[32], sWdt[128], sb[8], sA[8];
    int tid = threadIdx.x;
    if (tid < 32) sWbc[tid] = W_bc[tid];
    else if (tid < 160) sWdt[tid - 32] = W_dt[tid - 32];
    else if (tid < 168) sb[tid - 160] = dt_bias[tid - 160];
    else if (tid < 176) sA[tid - 168] = -expf(A_log[tid - 168]);
    __syncthreads();
    int gid = blockIdx.x * 256 + tid;          // (b*L + l)*Q + q
    if (gid >= BB * LL * QQ) return;
    int q = gid % QQ;
    int bl = gid / QQ;
    const float* dp = dist + (size_t)gid * 16;
    float d[16];
    float4 d0 = *(const float4*)(dp + 0);
    float4 d1 = *(const float4*)(dp + 4);
    float4 d2 = *(const float4*)(dp + 8);
    float4 d3 = *(const float4*)(dp + 12);
    d[0]=d0.x; d[1]=d0.y; d[2]=d0.z; d[3]=d0.w;
    d[4]=d1.x; d[5]=d1.y; d[6]=d1.z; d[7]=d1.w;
    d[8]=d2.x; d[9]=d2.y; d[10]=d2.z; d[11]=d2.w;
    d[12]=d3.x; d[13]=d3.y; d[14]=d3.z; d[15]=d3.w;
    float bc0 = 0.f, bc1 = 0.f;
#pragma unroll
    for (int m = 0; m < 16; m++) {
        bc0 = fmaf(d[m], sWbc[m], bc0);
        bc1 = fmaf(d[m], sWbc[16 + m], bc1);
    }
    float Bmv = bc0 + bias10[bl * 10 + 0];
    float Cv  = bc1 + bias10[bl * 10 + 1];
    Cm[bl * QP + q] = Cv;
#pragma unroll
    for (int h = 0; h < 8; h++) {
        float t = 0.f;
#pragma unroll
        for (int m = 0; m < 16; m++) t = fmaf(d[m], sWdt[h * 16 + m], t);
        float pre = t + bias10[bl * 10 + 2 + h] + sb[h];
        float dt = (pre > 20.f) ? pre : log1pf(expf(pre));
        int o = (bl * 8 + h) * QP + q;
        float2 v;
        v.x = expf(sA[h] * dt);      // dA
        v.y = dt * Bmv;              // dtB
        *(float2*)(dAB + (size_t)o * 2) = v;
    }
}

// ---------------------------------------------------------------------------
// Pass AC v4: segment-local march (S_in = 0), computes S_local, y^loc AND
// segd (segment decay product — order-independent, so the dir=0 march's
// running product equals k2b's forward product; k2b kernel deleted).
//
// NO LDS, NO BARRIERS: operands read per-lane directly from global
// (coalesced; dAB/Cm/zx are L2/L3-warm — staging cache-resident data was
// pure overhead, and barrier lockstep was the hidden stall in R5-R7).
// Manual 1-step register double-buffer hides L3 latency. Core math forced
// to packed v_pk_fma_f32 via inline asm.
//
// grid (NSEG*2, 32, 2): blockIdx.x = seg*2 + ph (p-half). Block 256 = 4
// waves; wave w owns p in [ph*32 + 8w, +8); lane owns n in {64k+lane}.
// S2[k*4+j] <-> (n = 64k+lane, p = p0+2j+{0,1}).
// ---------------------------------------------------------------------------
__global__ __launch_bounds__(256) void pass_ac(const float* __restrict__ dAB,
                                               const float* __restrict__ Cm,
                                               const float* __restrict__ zx,
                                               float* __restrict__ S_local,
                                               float* __restrict__ segd,
                                               float* __restrict__ yf,
                                               float* __restrict__ yb) {
    int seg = blockIdx.x >> 1, ph = blockIdx.x & 1;
    int bh = blockIdx.y, dir = blockIdx.z;
    int tid = threadIdx.x;
    int w = tid >> 6, lane = tid & 63;
    int p0 = ph * 32 + w * 8;
    int b = bh >> 3, h = bh & 7;
    f32x2 S2[20];
#pragma unroll
    for (int j = 0; j < 20; j++) S2[j] = {0.f, 0.f};
    float prodA[5];
#pragma unroll
    for (int k = 0; k < 5; k++) prodA[k] = 1.f;
    float* __restrict__ yo = dir ? yb : yf;
    bool s1 = (lane & 1) != 0, s2b = (lane & 2) != 0;

    auto LD = [&](int i, f32x2 (&AB)[5], float (&C)[5], float4 (&X)[2]) {
        int l = dir ? (LL - 1 - (seg * SEGLEN + i)) : (seg * SEGLEN + i);
        int bl = b * LL + l;
        const float* pa = dAB + (size_t)(bl * 8 + h) * (QP * 2);
        const float* pc = Cm + (size_t)bl * QP;
        const float* px = zx + (size_t)bl * 1024 + 512 + h * 64 + p0;
#pragma unroll
        for (int k = 0; k < 5; k++) {
            AB[k] = *(const f32x2*)(pa + 2 * (k * 64 + lane));
            C[k] = pc[k * 64 + lane];
        }
        X[0] = *(const float4*)(px);
        X[1] = *(const float4*)(px + 4);
    };

    auto STEP = [&](int i, f32x2 (&AB)[5], float (&C)[5], float4 (&X)[2]) {
        f32x2 x2[4] = {{X[0].x, X[0].y}, {X[0].z, X[0].w},
                       {X[1].x, X[1].y}, {X[1].z, X[1].w}};
        f32x2 y0 = {0.f, 0.f}, y1 = {0.f, 0.f}, y2v = {0.f, 0.f}, y3 = {0.f, 0.f};
#pragma unroll
        for (int k = 0; k < 5; k++) {
            f32x2 a2 = {AB[k].x, AB[k].x};
            f32x2 b2 = {AB[k].y, AB[k].y};
            f32x2 c2 = {C[k], C[k]};
            prodA[k] *= AB[k].x;
            f32x2 t, s;
            t = pk_mul(b2, x2[0]); s = pk_fma(S2[k * 4 + 0], a2, t); S2[k * 4 + 0] = s; y0  = pk_fma(s, c2, y0);
            t = pk_mul(b2, x2[1]); s = pk_fma(S2[k * 4 + 1], a2, t); S2[k * 4 + 1] = s; y1  = pk_fma(s, c2, y1);
            t = pk_mul(b2, x2[2]); s = pk_fma(S2[k * 4 + 2], a2, t); S2[k * 4 + 2] = s; y2v = pk_fma(s, c2, y2v);
            t = pk_mul(b2, x2[3]); s = pk_fma(S2[k * 4 + 3], a2, t); S2[k * 4 + 3] = s; y3  = pk_fma(s, c2, y3);
        }
        // reduce-scatter 4 p-pair items over 64 lanes; final item = (lane&3)
        f32x2 u, v, z0, z1, q;
        u = s1 ? y1 : y0;  v = s1 ? y0 : y1;   z0 = u + dpp2<0xB1>(v);
        u = s1 ? y3 : y2v; v = s1 ? y2v : y3;  z1 = u + dpp2<0xB1>(v);
        u = s2b ? z1 : z0; v = s2b ? z0 : z1;  q = u + dpp2<0x4E>(v);
        q = q + swz2<0x101F>(q);      // xor4
        q = q + dpp2<0x128>(q);       // xor8 (row_ror:8)
        q = q + swz2<0x401F>(q);      // xor16
        q = q + shfl_xor2(q, 32);     // xor32
        if (lane < 4) {
            int l = dir ? (LL - 1 - (seg * SEGLEN + i)) : (seg * SEGLEN + i);
            int bl = b * LL + l;
            *(f32x2*)(yo + (size_t)(bl * 8 + h) * 64 + p0 + 2 * lane) = q;
        }
    };

    f32x2 abA[5], abB[5];
    float cA[5], cB[5];
    float4 xA[2], xB[2];
    LD(0, abA, cA, xA);
#pragma unroll 1
    for (int i = 0; i < SEGLEN; i += 2) {
        LD(i + 1, abB, cB, xB);
        STEP(i, abA, cA, xA);
        if (i + 2 < SEGLEN) LD(i + 2, abA, cA, xA);
        STEP(i + 1, abB, cB, xB);
    }
    // epilogue: S_local (lane's 5 n-rows, 8 p's each)
    size_t base = (size_t)((dir * NSEG + seg) * 32 + bh) * QP * 64;
#pragma unroll
    for (int k = 0; k < 5; k++) {
        int n = k * 64 + lane;
        float4 v0 = {S2[k * 4 + 0].x, S2[k * 4 + 0].y, S2[k * 4 + 1].x, S2[k * 4 + 1].y};
        float4 v1 = {S2[k * 4 + 2].x, S2[k * 4 + 2].y, S2[k * 4 + 3].x, S2[k * 4 + 3].y};
        *(float4*)&S_local[base + (size_t)n * 64 + p0] = v0;
        *(float4*)&S_local[base + (size_t)n * 64 + p0 + 4] = v1;
    }
    // segd: product over the whole segment, order-independent -> dir0/ph0 writes
    if (dir == 0 && ph == 0 && w == 0) {
#pragma unroll
        for (int k = 0; k < 5; k++)
            segd[((b * NSEG + seg) * 8 + h) * QP + k * 64 + lane] = prodA[k];
    }
}

// ---------------------------------------------------------------------------
// Pass B: sequential segment combine (16 steps), writes S_in per segment and
// the averaged final state Savg (B,H,QP,P)
// ---------------------------------------------------------------------------
__global__ __launch_bounds__(256) void pass_b(const float* __restrict__ S_local,
                                              const float* __restrict__ segd,
                                              const float* __restrict__ S0q,
                                              float* __restrict__ S_in,
                                              float* __restrict__ Savg) {
    int gid = blockIdx.x * 256 + threadIdx.x;   // (b,h,n,p)
    if (gid >= BB * 8 * QP * 64) return;
    int p = gid & 63; int r = gid >> 6;
    int n = r % QP; r /= QP;
    int h = r & 7; int b = r >> 3;
    int bh = b * 8 + h;
    float s0 = (n < QQ) ? S0q[(size_t)(b * QQ + n) * 512 + h * 64 + p] : 0.f;
    float Sf = 0.f, Sb = 0.f;
    for (int dir = 0; dir < 2; dir++) {
        float S = s0;
        for (int s = 0; s < NSEG; s++) {
            size_t idx = (size_t)(((dir * NSEG + s) * 32 + bh) * QP + n) * 64 + p;
            S_in[idx] = S;
            int sf = dir ? (NSEG - 1 - s) : s;
            float dec = segd[((b * NSEG + sf) * 8 + h) * QP + n];
            S = fmaf(S, dec, S_local[idx]);
        }
        if (dir == 0) Sf = S; else Sb = S;
    }
    Savg[((bh) * QP + n) * 64 + p] = 0.5f * (Sf + Sb);
}

// ---------------------------------------------------------------------------
// K3_corr: y += Ahat @ S_in per (seg,bh,dir), where Ahat[i,n] = C_i[n] *
// cumprod_{k<=i} dA_k[n]. M=128 (steps), K=320 (n), N=64 (p).
// ---------------------------------------------------------------------------
__global__ __launch_bounds__(256) void k3_corr(const float* __restrict__ dAB,
                                               const float* __restrict__ Cm,
                                               const float* __restrict__ Sin,
                                               float* __restrict__ yf,
                                               float* __restrict__ yb) {
    __shared__ __align__(16) ushort_t sAh[128][48], sAl[128][48];  // 12 KB each
    __shared__ __align__(16) ushort_t sBh[64][48], sBl[64][48];    // 6 KB each
    __shared__ float pref[8][32];
    int seg = blockIdx.x, bh = blockIdx.y, dir = blockIdx.z;
    int b = bh >> 3, h = bh & 7;
    int tid = threadIdx.x;
    int w = tid >> 6, lane = tid & 63;
    int lm = lane & 15, lkq = lane >> 4;
    f32x4 acc[2][4];
#pragma unroll
    for (int i = 0; i < 2; i++)
#pragma unroll
        for (int j = 0; j < 4; j++) acc[i][j] = {0.f, 0.f, 0.f, 0.f};
    size_t sinBase = (size_t)((dir * NSEG + seg) * 32 + bh) * QP * 64;
    int nl = tid & 31, iseg = tid >> 5;   // cumprod roles: 32 n x 8 i-segments

    for (int k0 = 0; k0 < QP; k0 += 32) {
        __syncthreads();   // protect LDS reuse across chunks
        // ---- stage S_in chunk -> sB [p][k] split-bf16 ----
#pragma unroll
        for (int r = 0; r < 8; r++) {
            int flat = tid + r * 256;          // 0..2047
            int kn = flat >> 6, p = flat & 63;
            float v = Sin[sinBase + (size_t)(k0 + kn) * 64 + p];
            ushort_t hi, lo;
            bf16_split(v, hi, lo);
            sBh[p][kn] = hi;
            sBl[p][kn] = lo;
        }
        // ---- load dA/Cm for 16-step chain, local product ----
        float da[16], cm[16];
#pragma unroll
        for (int k = 0; k < 16; k++) {
            int i = iseg * 16 + k;
            int l = dir ? (LL - 1 - (seg * SEGLEN + i)) : (seg * SEGLEN + i);
            int bl = b * LL + l;
            da[k] = dAB[((size_t)(bl * 8 + h) * QP + k0 + nl) * 2];
            cm[k] = Cm[(size_t)bl * QP + k0 + nl];
        }
        float lp = 1.f;
#pragma unroll
        for (int k = 0; k < 16; k++) lp *= da[k];
        pref[iseg][nl] = lp;
        __syncthreads();
        if (tid < 32) {                       // exclusive prefix over i-segments
            float c = 1.f;
#pragma unroll
            for (int s = 0; s < 8; s++) {
                float t = pref[s][tid];
                pref[s][tid] = c;
                c *= t;
            }
        }
        __syncthreads();
        float cum = pref[iseg][nl];
#pragma unroll
        for (int k = 0; k < 16; k++) {
            cum *= da[k];
            float v = cum * cm[k];
            ushort_t hi, lo;
            bf16_split(v, hi, lo);
            int i = iseg * 16 + k;
            sAh[i][nl] = hi;
            sAl[i][nl] = lo;
        }
        __syncthreads();
        // ---- MFMA ----
        bf16x8 ah[2], al[2], bhf[4], blf[4];
#pragma unroll
        for (int mf = 0; mf < 2; mf++) {
            int row = w * 32 + mf * 16 + lm;
            ah[mf] = *(const bf16x8*)&sAh[row][lkq * 8];
            al[mf] = *(const bf16x8*)&sAl[row][lkq * 8];
        }
#pragma unroll
        for (int nf = 0; nf < 4; nf++) {
            int p = nf * 16 + lm;
            bhf[nf] = *(const bf16x8*)&sBh[p][lkq * 8];
            blf[nf] = *(const bf16x8*)&sBl[p][lkq * 8];
        }
#pragma unroll
        for (int mf = 0; mf < 2; mf++)
#pragma unroll
            for (int nf = 0; nf < 4; nf++) {
                acc[mf][nf] = __builtin_amdgcn_mfma_f32_16x16x32_bf16(ah[mf], bhf[nf], acc[mf][nf], 0, 0, 0);
                acc[mf][nf] = __builtin_amdgcn_mfma_f32_16x16x32_bf16(ah[mf], blf[nf], acc[mf][nf], 0, 0, 0);
                acc[mf][nf] = __builtin_amdgcn_mfma_f32_16x16x32_bf16(al[mf], bhf[nf], acc[mf][nf], 0, 0, 0);
            }
    }
    // ---- epilogue: y += correction ----
    float* __restrict__ yo = dir ? yb : yf;
#pragma unroll
    for (int mf = 0; mf < 2; mf++)
#pragma unroll
        for (int nf = 0; nf < 4; nf++)
#pragma unroll
            for (int r = 0; r < 4; r++) {
                int i = w * 32 + mf * 16 + lkq * 4 + r;
                int p = nf * 16 + lm;
                int l = dir ? (LL - 1 - (seg * SEGLEN + i)) : (seg * SEGLEN + i);
                size_t idx = (size_t)((b * LL + l) * 8 + h) * 64 + p;
                yo[idx] += acc[mf][nf][r];
            }
}

// ---------------------------------------------------------------------------
// K4: y = 0.5*(yf+yb) + Dp*x ; g = y*silu(z) ; key = g * rms(g) * key_norm_w
// ---------------------------------------------------------------------------
__global__ __launch_bounds__(512) void k4_gate(const float* __restrict__ yf,
                                               const float* __restrict__ yb,
                                               const float* __restrict__ zx,
                                               const float* __restrict__ Dp,
                                               const float* __restrict__ knw,
                                               ushort_t* __restrict__ kh,
                                               ushort_t* __restrict__ kl) {
    int bl = blockIdx.x;
    int t = threadIdx.x;
    int h = t >> 6;
    float x = zx[(size_t)bl * 1024 + 512 + t];
    float yv = 0.5f * (yf[(size_t)bl * 512 + t] + yb[(size_t)bl * 512 + t]) + Dp[h] * x;
    float z = zx[(size_t)bl * 1024 + t];
    float g = yv * (z / (1.f + expf(-z)));
    float v = g * g;
#pragma unroll
    for (int o = 32; o > 0; o >>= 1) v += __shfl_down(v, o, 64);
    __shared__ float rs[8];
    __shared__ float stot;
    if ((t & 63) == 0) rs[t >> 6] = v;
    __syncthreads();
    if (t == 0) {
        float s = 0.f;
#pragma unroll
        for (int i = 0; i < 8; i++) s += rs[i];
        stot = s;
    }
    __syncthreads();
    float rms = rsqrtf(stot / 512.f + 1e-5f);
    float kv = g * rms * knw[t];
    ushort_t hi, lo;
    bf16_split(kv, hi, lo);
    kh[(size_t)bl * 512 + t] = hi;
    kl[(size_t)bl * 512 + t] = lo;
}

// ---------------------------------------------------------------------------
// K5: layernorm on Savg rearranged to (B,Q,512); one block per (b,q).
// ---------------------------------------------------------------------------
__global__ __launch_bounds__(512) void k5_ln(const float* __restrict__ Savg,
                                             const float* __restrict__ lnw,
                                             const float* __restrict__ lnb,
                                             ushort_t* __restrict__ lh,
                                             ushort_t* __restrict__ ll) {
    int bq = blockIdx.x;
    int b = bq / QQ, q = bq % QQ;
    int t = threadIdx.x;
    int h = t >> 6, p = t & 63;
    float v = Savg[((b * 8 + h) * QP + q) * 64 + p];
    float s1 = v, s2 = v * v;
#pragma unroll
    for (int o = 32; o > 0; o >>= 1) {
        s1 += __shfl_down(s1, o, 64);
        s2 += __shfl_down(s2, o, 64);
    }
    __shared__ float r1[8], r2[8];
    __shared__ float smu, srv;
    if ((t & 63) == 0) { r1[t >> 6] = s1; r2[t >> 6] = s2; }
    __syncthreads();
    if (t == 0) {
        float a = 0.f, c = 0.f;
#pragma unroll
        for (int i = 0; i < 8; i++) { a += r1[i]; c += r2[i]; }
        float mu = a / 512.f;
        float var = c / 512.f - mu * mu;
        smu = mu;
        srv = rsqrtf(var + 1e-5f);
    }
    __syncthreads();
    float ov = (v - smu) * srv * lnw[t] + lnb[t];
    ushort_t hi, lo;
    bf16_split(ov, hi, lo);
    lh[(size_t)bq * 512 + t] = hi;
    ll[(size_t)bq * 512 + t] = lo;
}

// ---------------------------------------------------------------------------
extern "C" void kernel_launch(void* const* d_in, const int* in_sizes, int n_in,
                              void* d_out, int out_size, void* d_ws, size_t ws_size,
                              hipStream_t stream) {
    const float* in_key    = (const float*)d_in[0];
    const float* in_query  = (const float*)d_in[1];
    const float* dist      = (const float*)d_in[2];
    const float* W_key     = (const float*)d_in[3];
    const float* W_query   = (const float*)d_in[4];
    const float* W_bc      = (const float*)d_in[5];
    const float* W_dt      = (const float*)d_in[6];
    const float* dt_bias   = (const float*)d_in[7];
    const float* A_log     = (const float*)d_in[8];
    const float* Dp        = (const float*)d_in[9];
    const float* W_out_key = (const float*)d_in[10];
    const float* W_out_query = (const float*)d_in[11];
    const float* key_norm_w = (const float*)d_in[12];
    const float* ln_w      = (const float*)d_in[13];
    const float* ln_b      = (const float*)d_in[14];

    float* out_key = (float*)d_out;
    float* out_query = out_key + (size_t)BB * LL * D_MODEL;   // 2,097,152

    char* w8 = (char*)d_ws;
    auto alloc = [&](size_t bytes) {
        char* ptr = w8;
        w8 += (bytes + 255) & ~(size_t)255;
        return ptr;
    };
    float* zx     = (float*)alloc((size_t)8192 * 1024 * 4);
    float* bias10 = (float*)alloc((size_t)8192 * 10 * 4);
    float* S0q    = (float*)alloc((size_t)1200 * 512 * 4);
    float* dABb   = (float*)alloc((size_t)8192 * 8 * QP * 2 * 4);   // packed {dA,dtB}
    float* Cmb    = (float*)alloc((size_t)8192 * QP * 4);
    float* segd   = (float*)alloc((size_t)BB * NSEG * 8 * QP * 4);
    float* Sloc   = (float*)alloc((size_t)2 * NSEG * 32 * QP * 64 * 4);
    float* Sin    = (float*)alloc((size_t)2 * NSEG * 32 * QP * 64 * 4);
    float* yfb    = (float*)alloc((size_t)8192 * 512 * 4);
    float* ybb    = (float*)alloc((size_t)8192 * 512 * 4);
    float* Savg   = (float*)alloc((size_t)32 * QP * 64 * 4);
    ushort_t* ink_h  = (ushort_t*)alloc((size_t)2097152 * 2);
    ushort_t* ink_l  = (ushort_t*)alloc((size_t)2097152 * 2);
    ushort_t* wk_h   = (ushort_t*)alloc((size_t)262144 * 2);
    ushort_t* wk_l   = (ushort_t*)alloc((size_t)262144 * 2);
    ushort_t* inq_h  = (ushort_t*)alloc((size_t)307200 * 2);
    ushort_t* inq_l  = (ushort_t*)alloc((size_t)307200 * 2);
    ushort_t* wq_h   = (ushort_t*)alloc((size_t)131072 * 2);
    ushort_t* wq_l   = (ushort_t*)alloc((size_t)131072 * 2);
    ushort_t* keyb_h = (ushort_t*)alloc((size_t)4194304 * 2);
    ushort_t* keyb_l = (ushort_t*)alloc((size_t)4194304 * 2);
    ushort_t* wok_h  = (ushort_t*)alloc((size_t)131072 * 2);
    ushort_t* wok_l  = (ushort_t*)alloc((size_t)131072 * 2);
    ushort_t* lsn_h  = (ushort_t*)alloc((size_t)614400 * 2);
    ushort_t* lsn_l  = (ushort_t*)alloc((size_t)614400 * 2);
    ushort_t* woq_h  = (ushort_t*)alloc((size_t)131072 * 2);
    ushort_t* woq_l  = (ushort_t*)alloc((size_t)131072 * 2);

    // Input conversions (bf16 hi/lo)
    c_split<<<8192, 256, 0, stream>>>(in_key, ink_h, ink_l, 2097152);
    c_split<<<1024, 256, 0, stream>>>(W_key, wk_h, wk_l, 262144);       // rows 0..1023
    c_split<<<1200, 256, 0, stream>>>(in_query, inq_h, inq_l, 307200);
    c_split<<<512, 256, 0, stream>>>(W_query, wq_h, wq_l, 131072);
    c_split<<<512, 256, 0, stream>>>(W_out_key, wok_h, wok_l, 131072);
    c_split<<<512, 256, 0, stream>>>(W_out_query, woq_h, woq_l, 131072);

    // Projections
    gemm_bf16s<<<dim3(16, 64), 256, 0, stream>>>(ink_h, ink_l, wk_h, wk_l, zx, 8192, 1024, 256);
    k1b_bias<<<2048, 256, 0, stream>>>(in_key, W_key, bias10);
    gemm_bf16s<<<dim3(8, 10), 256, 0, stream>>>(inq_h, inq_l, wq_h, wq_l, S0q, 1200, 512, 256);

    // dist -> packed {dA,dtB}, Cm
    k2_dist<<<9600, 256, 0, stream>>>(dist, bias10, W_bc, W_dt, dt_bias, A_log, dABb, Cmb);

    // segmented bidirectional scan: march (also emits segd) + combine + MFMA corr
    pass_ac<<<dim3(NSEG * 2, 32, 2), 256, 0, stream>>>(dABb, Cmb, zx, Sloc, segd, yfb, ybb);
    pass_b<<<2560, 256, 0, stream>>>(Sloc, segd, S0q, Sin, Savg);
    k3_corr<<<dim3(NSEG, 32, 2), 256, 0, stream>>>(dABb, Cmb, Sin, yfb, ybb);

    // out_key path (k4 writes split-bf16 directly)
    k4_gate<<<8192, 512, 0, stream>>>(yfb, ybb, zx, Dp, key_norm_w, keyb_h, keyb_l);
    gemm_bf16s<<<dim3(4, 64), 256, 0, stream>>>(keyb_h, keyb_l, wok_h, wok_l, out_key, 8192, 256, 512);

    // out_query path (k5 writes split-bf16 directly)
    k5_ln<<<1200, 512, 0, stream>>>(Savg, ln_w, ln_b, lsn_h, lsn_l);
    gemm_bf16s<<<dim3(4, 10), 256, 0, stream>>>(lsn_h, lsn_l, woq_h, woq_l, out_query, 1200, 256, 512);
}

// Round 6
// 932.564 us; speedup vs baseline: 1.0483x; 1.0483x over previous
//
#include <hip/hip_runtime.h>
#include <hip/hip_bf16.h>

// Problem constants
#define D_MODEL 256
#define D_INNER 512
#define NHEADS 8
#define HEADDIM 64
#define MDIST 16
#define BB 4
#define LL 2048
#define QQ 300
#define QP 320          // padded Q
#define NSEG 16
#define SEGLEN 128      // LL / NSEG

typedef unsigned short ushort_t;
typedef __attribute__((ext_vector_type(8))) short bf16x8;
typedef __attribute__((ext_vector_type(4))) float f32x4;
typedef __attribute__((ext_vector_type(2))) float f32x2;

__device__ __forceinline__ void bf16_split(float v, ushort_t& hi, ushort_t& lo) {
    __hip_bfloat16 h = __float2bfloat16(v);
    float hf = __bfloat162float(h);
    __hip_bfloat16 l = __float2bfloat16(v - hf);
    hi = *(ushort_t*)&h;
    lo = *(ushort_t*)&l;
}

__device__ __forceinline__ f32x2 shfl_xor2(f32x2 v, int m) {
    f32x2 r;
    r.x = __shfl_xor(v.x, m, 64);
    r.y = __shfl_xor(v.y, m, 64);
    return r;
}

// DPP cross-lane move (VALU pipe, NOT the shared DS pipe).
// quad_perm 0xB1 = xor1, 0x4E = xor2, 0x128 = row_ror:8 (xor8 within row of 16).
template<int CTRL>
__device__ __forceinline__ f32x2 dpp2(f32x2 v) {
    f32x2 r;
    r.x = __int_as_float(__builtin_amdgcn_update_dpp(0, __float_as_int(v.x), CTRL, 0xF, 0xF, true));
    r.y = __int_as_float(__builtin_amdgcn_update_dpp(0, __float_as_int(v.y), CTRL, 0xF, 0xF, true));
    return r;
}
// ds_swizzle xor patterns: 0x101F = xor4, 0x401F = xor16
template<int OFF>
__device__ __forceinline__ f32x2 swz2(f32x2 v) {
    f32x2 r;
    r.x = __int_as_float(__builtin_amdgcn_ds_swizzle(__float_as_int(v.x), OFF));
    r.y = __int_as_float(__builtin_amdgcn_ds_swizzle(__float_as_int(v.y), OFF));
    return r;
}

// Packed fp32 math forced via asm (guaranteed single-issue VOP3P).
__device__ __forceinline__ f32x2 pk_mul(f32x2 a, f32x2 b) {
    f32x2 d;
    asm("v_pk_mul_f32 %0, %1, %2" : "=v"(d) : "v"(a), "v"(b));
    return d;
}
__device__ __forceinline__ f32x2 pk_fma(f32x2 a, f32x2 b, f32x2 c) {
    f32x2 d;
    asm("v_pk_fma_f32 %0, %1, %2, %3" : "=v"(d) : "v"(a), "v"(b), "v"(c));
    return d;
}

// ---------------------------------------------------------------------------
// Split fp32 -> bf16 hi + bf16 lo (residual). C = Ah*Bh + Ah*Bl + Al*Bh gives
// ~fp32 accuracy (missing Al*Bl term ~2^-18 relative).
// ---------------------------------------------------------------------------
__global__ __launch_bounds__(256) void c_split(const float* __restrict__ in,
                                               ushort_t* __restrict__ hi,
                                               ushort_t* __restrict__ lo, int n) {
    int i = blockIdx.x * 256 + threadIdx.x;
    if (i >= n) return;
    ushort_t h, l;
    bf16_split(in[i], h, l);
    hi[i] = h;
    lo[i] = l;
}

// ---------------------------------------------------------------------------
// Split-bf16 MFMA GEMM: C[M,N] = A[M,K] * B[N,K]^T (NT), fp32 out.
// ---------------------------------------------------------------------------
__global__ __launch_bounds__(256) void gemm_bf16s(const ushort_t* __restrict__ Ah,
                                                  const ushort_t* __restrict__ Al,
                                                  const ushort_t* __restrict__ Bh,
                                                  const ushort_t* __restrict__ Bl,
                                                  float* __restrict__ C,
                                                  int M, int N, int K) {
    int w = threadIdx.x >> 6, lane = threadIdx.x & 63;
    int n0 = blockIdx.x * 64;
    int m0 = blockIdx.y * 128 + w * 32;
    int lm = lane & 15, lk = (lane >> 4) * 8;
    f32x4 acc[2][4];
#pragma unroll
    for (int i = 0; i < 2; i++)
#pragma unroll
        for (int j = 0; j < 4; j++) acc[i][j] = {0.f, 0.f, 0.f, 0.f};

    for (int k0 = 0; k0 < K; k0 += 32) {
        bf16x8 ah[2], al[2], bh[4], blo[4];
#pragma unroll
        for (int mf = 0; mf < 2; mf++) {
            int row = m0 + mf * 16 + lm;
            if (row >= M) row = M - 1;            // safe clamp; epilogue guards
            size_t off = (size_t)row * K + k0 + lk;
            ah[mf] = *(const bf16x8*)(Ah + off);
            al[mf] = *(const bf16x8*)(Al + off);
        }
#pragma unroll
        for (int nf = 0; nf < 4; nf++) {
            int col = n0 + nf * 16 + lm;
            size_t off = (size_t)col * K + k0 + lk;
            bh[nf]  = *(const bf16x8*)(Bh + off);
            blo[nf] = *(const bf16x8*)(Bl + off);
        }
#pragma unroll
        for (int mf = 0; mf < 2; mf++)
#pragma unroll
            for (int nf = 0; nf < 4; nf++) {
                acc[mf][nf] = __builtin_amdgcn_mfma_f32_16x16x32_bf16(ah[mf], bh[nf],  acc[mf][nf], 0, 0, 0);
                acc[mf][nf] = __builtin_amdgcn_mfma_f32_16x16x32_bf16(ah[mf], blo[nf], acc[mf][nf], 0, 0, 0);
                acc[mf][nf] = __builtin_amdgcn_mfma_f32_16x16x32_bf16(al[mf], bh[nf],  acc[mf][nf], 0, 0, 0);
            }
    }
#pragma unroll
    for (int mf = 0; mf < 2; mf++)
#pragma unroll
        for (int nf = 0; nf < 4; nf++)
#pragma unroll
            for (int r = 0; r < 4; r++) {
                int m = m0 + mf * 16 + (lane >> 4) * 4 + r;
                if (m < M) C[(size_t)m * N + n0 + nf * 16 + lm] = acc[mf][nf][r];
            }
}

// ---------------------------------------------------------------------------
// K1b: fp32 bias columns (rows 1024..1033 of W_key) — precision-critical.
// ---------------------------------------------------------------------------
__global__ __launch_bounds__(256) void k1b_bias(const float* __restrict__ in_key,
                                                const float* __restrict__ W_key,
                                                float* __restrict__ bias10) {
    int w = threadIdx.x >> 6, lane = threadIdx.x & 63;
    int row = blockIdx.x * 4 + w;
    float4 a = *(const float4*)(in_key + (size_t)row * 256 + lane * 4);
#pragma unroll
    for (int c = 0; c < 10; c++) {
        float4 b = *(const float4*)(W_key + (size_t)(1024 + c) * 256 + lane * 4);
        float t = a.x * b.x + a.y * b.y + a.z * b.z + a.w * b.w;
#pragma unroll
        for (int o = 32; o > 0; o >>= 1) t += __shfl_down(t, o, 64);
        if (lane == 0) bias10[row * 10 + c] = t;
    }
}

// ---------------------------------------------------------------------------
// K2: dist (B,L,Q,16) -> dAB (B,L,H,QP,{dA,dtB}) packed float2, Cm (B,L,QP).
// ---------------------------------------------------------------------------
__global__ __launch_bounds__(256) void k2_dist(const float* __restrict__ dist,
                                               const float* __restrict__ bias10,
                                               const float* __restrict__ W_bc,
                                               const float* __restrict__ W_dt,
                                               const float* __restrict__ dt_bias,
                                               const float* __restrict__ A_log,
                                               float* __restrict__ dAB,
                                               float* __restrict__ Cm) {
    __shared__ float sWbc[32], sWdt[128], sb[8], sA[8];
    int tid = threadIdx.x;
    if (tid < 32) sWbc[tid] = W_bc[tid];
    else if (tid < 160) sWdt[tid - 32] = W_dt[tid - 32];
    else if (tid < 168) sb[tid - 160] = dt_bias[tid - 160];
    else if (tid < 176) sA[tid - 168] = -expf(A_log[tid - 168]);
    __syncthreads();
    int gid = blockIdx.x * 256 + tid;          // (b*L + l)*Q + q
    if (gid >= BB * LL * QQ) return;
    int q = gid % QQ;
    int bl = gid / QQ;
    const float* dp = dist + (size_t)gid * 16;
    float d[16];
    float4 d0 = *(const float4*)(dp + 0);
    float4 d1 = *(const float4*)(dp + 4);
    float4 d2 = *(const float4*)(dp + 8);
    float4 d3 = *(const float4*)(dp + 12);
    d[0]=d0.x; d[1]=d0.y; d[2]=d0.z; d[3]=d0.w;
    d[4]=d1.x; d[5]=d1.y; d[6]=d1.z; d[7]=d1.w;
    d[8]=d2.x; d[9]=d2.y; d[10]=d2.z; d[11]=d2.w;
    d[12]=d3.x; d[13]=d3.y; d[14]=d3.z; d[15]=d3.w;
    float bc0 = 0.f, bc1 = 0.f;
#pragma unroll
    for (int m = 0; m < 16; m++) {
        bc0 = fmaf(d[m], sWbc[m], bc0);
        bc1 = fmaf(d[m], sWbc[16 + m], bc1);
    }
    float Bmv = bc0 + bias10[bl * 10 + 0];
    float Cv  = bc1 + bias10[bl * 10 + 1];
    Cm[bl * QP + q] = Cv;
#pragma unroll
    for (int h = 0; h < 8; h++) {
        float t = 0.f;
#pragma unroll
        for (int m = 0; m < 16; m++) t = fmaf(d[m], sWdt[h * 16 + m], t);
        float pre = t + bias10[bl * 10 + 2 + h] + sb[h];
        float dt = (pre > 20.f) ? pre : log1pf(expf(pre));
        int o = (bl * 8 + h) * QP + q;
        float2 v;
        v.x = expf(sA[h] * dt);      // dA
        v.y = dt * Bmv;              // dtB
        *(float2*)(dAB + (size_t)o * 2) = v;
    }
}

// ---------------------------------------------------------------------------
// Pass AC (R4-measured structure, 313 µs; + fused segd, + asm pk math):
// segment-local march (S_in = 0), computes S_local, y^loc AND segd (the
// segment decay product is order-independent, so the dir=0 march's running
// product equals the forward product; k2b kernel deleted).
//
// grid (NSEG, 32, 2), block 256 = 4 waves; wave w owns p in [16w, 16w+16),
// lane owns n in {64k+lane, k=0..4} -> S2[40] f32x2.
// G=4 LDS staging (32 KB, double-buffered), barrier per 4 steps.
// y-reduction: DPP quad_perm/row_ror on the VALU pipe; only xor4/xor16
// ds_swizzle + xor32 shfl touch the DS pipe.
// Cost model (validated R4): ~15 DS-ops/wave-step x 16 waves/CU x ~5cyc
// ~= 1200 cyc/step-slot -> ~300 µs; VALU floor ~100 µs.
// ---------------------------------------------------------------------------
__global__ __launch_bounds__(256) void pass_ac(const float* __restrict__ dAB,
                                               const float* __restrict__ Cm,
                                               const float* __restrict__ zx,
                                               float* __restrict__ S_local,
                                               float* __restrict__ segd,
                                               float* __restrict__ yf,
                                               float* __restrict__ yb) {
    __shared__ __align__(16) float sOp[2][4096];   // 32 KB: 4 steps x [ab 640 | c 320 | x 64]
    int seg = blockIdx.x, bh = blockIdx.y, dir = blockIdx.z;
    int tid = threadIdx.x;
    int w = tid >> 6, lane = tid & 63;
    int p0 = w * 16;
    int b = bh >> 3, h = bh & 7;
    f32x2 S2[40];                    // S2[k*8+j] <-> (n = 64k+lane, p = p0+2j+{0,1})
#pragma unroll
    for (int j = 0; j < 40; j++) S2[j] = {0.f, 0.f};
    float prodA[5];
#pragma unroll
    for (int k = 0; k < 5; k++) prodA[k] = 1.f;
    float* __restrict__ yo = dir ? yb : yf;
    bool s1 = (lane & 1) != 0, s2b = (lane & 2) != 0, s4 = (lane & 4) != 0;

    int pos = tid * 4;               // this thread's 4-float slice of each step
    auto stage = [&](int g, int buf) {
#pragma unroll
        for (int r = 0; r < 4; r++) {
            int i = g * 4 + r;
            int l = dir ? (LL - 1 - (seg * SEGLEN + i)) : (seg * SEGLEN + i);
            int bl = b * LL + l;
            const float* src;
            if (pos < 640)      src = dAB + (size_t)(bl * 8 + h) * 640 + pos;
            else if (pos < 960) src = Cm + (size_t)bl * QP + (pos - 640);
            else                src = zx + (size_t)bl * 1024 + 512 + h * 64 + (pos - 960);
            *(float4*)&sOp[buf][r * 1024 + pos] = *(const float4*)src;
        }
    };
    stage(0, 0);
    const int NGRP = SEGLEN / 4;          // 32 groups of 4 steps
    for (int g = 0; g < NGRP; g++) {
        __syncthreads();
        if (g + 1 < NGRP) stage(g + 1, (g + 1) & 1);
        const float* bufg = &sOp[g & 1][0];
#pragma unroll
        for (int it = 0; it < 4; it++) {
            const float* Bq = bufg + it * 1024;
            // x: wave-uniform 16 floats (broadcast b128 reads)
            float4 xq0 = *(const float4*)(Bq + 960 + p0);
            float4 xq1 = *(const float4*)(Bq + 964 + p0);
            float4 xq2 = *(const float4*)(Bq + 968 + p0);
            float4 xq3 = *(const float4*)(Bq + 972 + p0);
            f32x2 x2[8] = {{xq0.x, xq0.y}, {xq0.z, xq0.w}, {xq1.x, xq1.y}, {xq1.z, xq1.w},
                           {xq2.x, xq2.y}, {xq2.z, xq2.w}, {xq3.x, xq3.y}, {xq3.z, xq3.w}};
            f32x2 y[8];
#pragma unroll
            for (int j = 0; j < 8; j++) y[j] = {0.f, 0.f};
#pragma unroll
            for (int k = 0; k < 5; k++) {
                int n = k * 64 + lane;
                f32x2 ab = *(const f32x2*)(Bq + 2 * n);     // {dA, dtB}, b64 unique
                float c = Bq[640 + n];                      // b32 unique
                f32x2 a2 = {ab.x, ab.x}, b2 = {ab.y, ab.y}, c2 = {c, c};
                prodA[k] *= ab.x;
#pragma unroll
                for (int j = 0; j < 8; j++) {
                    f32x2 t = pk_mul(b2, x2[j]);
                    f32x2 s = pk_fma(S2[k * 8 + j], a2, t);
                    S2[k * 8 + j] = s;
                    y[j] = pk_fma(s, c2, y[j]);
                }
            }
            // reduce-scatter 8 items over 64 lanes; final item (lane&7)
            // L1/L2: DPP quad_perm (VALU); L4: swizzle; L8: DPP ror; L16: swizzle; L32: shfl
            f32x2 u, v, z0, z1, z2, z3, w0, w1, q;
            u = s1 ? y[1] : y[0]; v = s1 ? y[0] : y[1]; z0 = u + dpp2<0xB1>(v);
            u = s1 ? y[3] : y[2]; v = s1 ? y[2] : y[3]; z1 = u + dpp2<0xB1>(v);
            u = s1 ? y[5] : y[4]; v = s1 ? y[4] : y[5]; z2 = u + dpp2<0xB1>(v);
            u = s1 ? y[7] : y[6]; v = s1 ? y[6] : y[7]; z3 = u + dpp2<0xB1>(v);
            u = s2b ? z1 : z0; v = s2b ? z0 : z1; w0 = u + dpp2<0x4E>(v);
            u = s2b ? z3 : z2; v = s2b ? z2 : z3; w1 = u + dpp2<0x4E>(v);
            u = s4 ? w1 : w0; v = s4 ? w0 : w1; q = u + swz2<0x101F>(v);
            q = q + dpp2<0x128>(q);       // xor8 (row_ror:8)
            q = q + swz2<0x401F>(q);      // xor16
            q = q + shfl_xor2(q, 32);     // xor32
            if (lane < 8) {
                int i = g * 4 + it;
                int l = dir ? (LL - 1 - (seg * SEGLEN + i)) : (seg * SEGLEN + i);
                int bl = b * LL + l;
                *(f32x2*)(yo + (size_t)(bl * 8 + h) * 64 + p0 + 2 * lane) = q;
            }
        }
    }
    // epilogue: store S_local (lane's 5 n-rows, 16 p's each)
    size_t base = (size_t)((dir * NSEG + seg) * 32 + bh) * QP * 64;
#pragma unroll
    for (int k = 0; k < 5; k++) {
        int n = k * 64 + lane;
#pragma unroll
        for (int t = 0; t < 4; t++) {
            float4 vv = {S2[k * 8 + 2 * t].x, S2[k * 8 + 2 * t].y,
                         S2[k * 8 + 2 * t + 1].x, S2[k * 8 + 2 * t + 1].y};
            *(float4*)&S_local[base + (size_t)n * 64 + p0 + 4 * t] = vv;
        }
    }
    // segd: product over the whole segment, order-independent -> dir0/w0 writes
    if (dir == 0 && w == 0) {
#pragma unroll
        for (int k = 0; k < 5; k++)
            segd[((b * NSEG + seg) * 8 + h) * QP + k * 64 + lane] = prodA[k];
    }
}

// ---------------------------------------------------------------------------
// Pass B: sequential segment combine (16 steps), writes S_in per segment and
// the averaged final state Savg (B,H,QP,P)
// ---------------------------------------------------------------------------
__global__ __launch_bounds__(256) void pass_b(const float* __restrict__ S_local,
                                              const float* __restrict__ segd,
                                              const float* __restrict__ S0q,
                                              float* __restrict__ S_in,
                                              float* __restrict__ Savg) {
    int gid = blockIdx.x * 256 + threadIdx.x;   // (b,h,n,p)
    if (gid >= BB * 8 * QP * 64) return;
    int p = gid & 63; int r = gid >> 6;
    int n = r % QP; r /= QP;
    int h = r & 7; int b = r >> 3;
    int bh = b * 8 + h;
    float s0 = (n < QQ) ? S0q[(size_t)(b * QQ + n) * 512 + h * 64 + p] : 0.f;
    float Sf = 0.f, Sb = 0.f;
    for (int dir = 0; dir < 2; dir++) {
        float S = s0;
        for (int s = 0; s < NSEG; s++) {
            size_t idx = (size_t)(((dir * NSEG + s) * 32 + bh) * QP + n) * 64 + p;
            S_in[idx] = S;
            int sf = dir ? (NSEG - 1 - s) : s;
            float dec = segd[((b * NSEG + sf) * 8 + h) * QP + n];
            S = fmaf(S, dec, S_local[idx]);
        }
        if (dir == 0) Sf = S; else Sb = S;
    }
    Savg[((bh) * QP + n) * 64 + p] = 0.5f * (Sf + Sb);
}

// ---------------------------------------------------------------------------
// K3_corr: y += Ahat @ S_in per (seg,bh,dir), where Ahat[i,n] = C_i[n] *
// cumprod_{k<=i} dA_k[n]. M=128 (steps), K=320 (n), N=64 (p).
// ---------------------------------------------------------------------------
__global__ __launch_bounds__(256) void k3_corr(const float* __restrict__ dAB,
                                               const float* __restrict__ Cm,
                                               const float* __restrict__ Sin,
                                               float* __restrict__ yf,
                                               float* __restrict__ yb) {
    __shared__ __align__(16) ushort_t sAh[128][48], sAl[128][48];  // 12 KB each
    __shared__ __align__(16) ushort_t sBh[64][48], sBl[64][48];    // 6 KB each
    __shared__ float pref[8][32];
    int seg = blockIdx.x, bh = blockIdx.y, dir = blockIdx.z;
    int b = bh >> 3, h = bh & 7;
    int tid = threadIdx.x;
    int w = tid >> 6, lane = tid & 63;
    int lm = lane & 15, lkq = lane >> 4;
    f32x4 acc[2][4];
#pragma unroll
    for (int i = 0; i < 2; i++)
#pragma unroll
        for (int j = 0; j < 4; j++) acc[i][j] = {0.f, 0.f, 0.f, 0.f};
    size_t sinBase = (size_t)((dir * NSEG + seg) * 32 + bh) * QP * 64;
    int nl = tid & 31, iseg = tid >> 5;   // cumprod roles: 32 n x 8 i-segments

    for (int k0 = 0; k0 < QP; k0 += 32) {
        __syncthreads();   // protect LDS reuse across chunks
        // ---- stage S_in chunk -> sB [p][k] split-bf16 ----
#pragma unroll
        for (int r = 0; r < 8; r++) {
            int flat = tid + r * 256;          // 0..2047
            int kn = flat >> 6, p = flat & 63;
            float v = Sin[sinBase + (size_t)(k0 + kn) * 64 + p];
            ushort_t hi, lo;
            bf16_split(v, hi, lo);
            sBh[p][kn] = hi;
            sBl[p][kn] = lo;
        }
        // ---- load dA/Cm for 16-step chain, local product ----
        float da[16], cm[16];
#pragma unroll
        for (int k = 0; k < 16; k++) {
            int i = iseg * 16 + k;
            int l = dir ? (LL - 1 - (seg * SEGLEN + i)) : (seg * SEGLEN + i);
            int bl = b * LL + l;
            da[k] = dAB[((size_t)(bl * 8 + h) * QP + k0 + nl) * 2];
            cm[k] = Cm[(size_t)bl * QP + k0 + nl];
        }
        float lp = 1.f;
#pragma unroll
        for (int k = 0; k < 16; k++) lp *= da[k];
        pref[iseg][nl] = lp;
        __syncthreads();
        if (tid < 32) {                       // exclusive prefix over i-segments
            float c = 1.f;
#pragma unroll
            for (int s = 0; s < 8; s++) {
                float t = pref[s][tid];
                pref[s][tid] = c;
                c *= t;
            }
        }
        __syncthreads();
        float cum = pref[iseg][nl];
#pragma unroll
        for (int k = 0; k < 16; k++) {
            cum *= da[k];
            float v = cum * cm[k];
            ushort_t hi, lo;
            bf16_split(v, hi, lo);
            int i = iseg * 16 + k;
            sAh[i][nl] = hi;
            sAl[i][nl] = lo;
        }
        __syncthreads();
        // ---- MFMA ----
        bf16x8 ah[2], al[2], bhf[4], blf[4];
#pragma unroll
        for (int mf = 0; mf < 2; mf++) {
            int row = w * 32 + mf * 16 + lm;
            ah[mf] = *(const bf16x8*)&sAh[row][lkq * 8];
            al[mf] = *(const bf16x8*)&sAl[row][lkq * 8];
        }
#pragma unroll
        for (int nf = 0; nf < 4; nf++) {
            int p = nf * 16 + lm;
            bhf[nf] = *(const bf16x8*)&sBh[p][lkq * 8];
            blf[nf] = *(const bf16x8*)&sBl[p][lkq * 8];
        }
#pragma unroll
        for (int mf = 0; mf < 2; mf++)
#pragma unroll
            for (int nf = 0; nf < 4; nf++) {
                acc[mf][nf] = __builtin_amdgcn_mfma_f32_16x16x32_bf16(ah[mf], bhf[nf], acc[mf][nf], 0, 0, 0);
                acc[mf][nf] = __builtin_amdgcn_mfma_f32_16x16x32_bf16(ah[mf], blf[nf], acc[mf][nf], 0, 0, 0);
                acc[mf][nf] = __builtin_amdgcn_mfma_f32_16x16x32_bf16(al[mf], bhf[nf], acc[mf][nf], 0, 0, 0);
            }
    }
    // ---- epilogue: y += correction ----
    float* __restrict__ yo = dir ? yb : yf;
#pragma unroll
    for (int mf = 0; mf < 2; mf++)
#pragma unroll
        for (int nf = 0; nf < 4; nf++)
#pragma unroll
            for (int r = 0; r < 4; r++) {
                int i = w * 32 + mf * 16 + lkq * 4 + r;
                int p = nf * 16 + lm;
                int l = dir ? (LL - 1 - (seg * SEGLEN + i)) : (seg * SEGLEN + i);
                size_t idx = (size_t)((b * LL + l) * 8 + h) * 64 + p;
                yo[idx] += acc[mf][nf][r];
            }
}

// ---------------------------------------------------------------------------
// K4: y = 0.5*(yf+yb) + Dp*x ; g = y*silu(z) ; key = g * rms(g) * key_norm_w
// ---------------------------------------------------------------------------
__global__ __launch_bounds__(512) void k4_gate(const float* __restrict__ yf,
                                               const float* __restrict__ yb,
                                               const float* __restrict__ zx,
                                               const float* __restrict__ Dp,
                                               const float* __restrict__ knw,
                                               ushort_t* __restrict__ kh,
                                               ushort_t* __restrict__ kl) {
    int bl = blockIdx.x;
    int t = threadIdx.x;
    int h = t >> 6;
    float x = zx[(size_t)bl * 1024 + 512 + t];
    float yv = 0.5f * (yf[(size_t)bl * 512 + t] + yb[(size_t)bl * 512 + t]) + Dp[h] * x;
    float z = zx[(size_t)bl * 1024 + t];
    float g = yv * (z / (1.f + expf(-z)));
    float v = g * g;
#pragma unroll
    for (int o = 32; o > 0; o >>= 1) v += __shfl_down(v, o, 64);
    __shared__ float rs[8];
    __shared__ float stot;
    if ((t & 63) == 0) rs[t >> 6] = v;
    __syncthreads();
    if (t == 0) {
        float s = 0.f;
#pragma unroll
        for (int i = 0; i < 8; i++) s += rs[i];
        stot = s;
    }
    __syncthreads();
    float rms = rsqrtf(stot / 512.f + 1e-5f);
    float kv = g * rms * knw[t];
    ushort_t hi, lo;
    bf16_split(kv, hi, lo);
    kh[(size_t)bl * 512 + t] = hi;
    kl[(size_t)bl * 512 + t] = lo;
}

// ---------------------------------------------------------------------------
// K5: layernorm on Savg rearranged to (B,Q,512); one block per (b,q).
// ---------------------------------------------------------------------------
__global__ __launch_bounds__(512) void k5_ln(const float* __restrict__ Savg,
                                             const float* __restrict__ lnw,
                                             const float* __restrict__ lnb,
                                             ushort_t* __restrict__ lh,
                                             ushort_t* __restrict__ ll) {
    int bq = blockIdx.x;
    int b = bq / QQ, q = bq % QQ;
    int t = threadIdx.x;
    int h = t >> 6, p = t & 63;
    float v = Savg[((b * 8 + h) * QP + q) * 64 + p];
    float s1 = v, s2 = v * v;
#pragma unroll
    for (int o = 32; o > 0; o >>= 1) {
        s1 += __shfl_down(s1, o, 64);
        s2 += __shfl_down(s2, o, 64);
    }
    __shared__ float r1[8], r2[8];
    __shared__ float smu, srv;
    if ((t & 63) == 0) { r1[t >> 6] = s1; r2[t >> 6] = s2; }
    __syncthreads();
    if (t == 0) {
        float a = 0.f, c = 0.f;
#pragma unroll
        for (int i = 0; i < 8; i++) { a += r1[i]; c += r2[i]; }
        float mu = a / 512.f;
        float var = c / 512.f - mu * mu;
        smu = mu;
        srv = rsqrtf(var + 1e-5f);
    }
    __syncthreads();
    float ov = (v - smu) * srv * lnw[t] + lnb[t];
    ushort_t hi, lo;
    bf16_split(ov, hi, lo);
    lh[(size_t)bq * 512 + t] = hi;
    ll[(size_t)bq * 512 + t] = lo;
}

// ---------------------------------------------------------------------------
extern "C" void kernel_launch(void* const* d_in, const int* in_sizes, int n_in,
                              void* d_out, int out_size, void* d_ws, size_t ws_size,
                              hipStream_t stream) {
    const float* in_key    = (const float*)d_in[0];
    const float* in_query  = (const float*)d_in[1];
    const float* dist      = (const float*)d_in[2];
    const float* W_key     = (const float*)d_in[3];
    const float* W_query   = (const float*)d_in[4];
    const float* W_bc      = (const float*)d_in[5];
    const float* W_dt      = (const float*)d_in[6];
    const float* dt_bias   = (const float*)d_in[7];
    const float* A_log     = (const float*)d_in[8];
    const float* Dp        = (const float*)d_in[9];
    const float* W_out_key = (const float*)d_in[10];
    const float* W_out_query = (const float*)d_in[11];
    const float* key_norm_w = (const float*)d_in[12];
    const float* ln_w      = (const float*)d_in[13];
    const float* ln_b      = (const float*)d_in[14];

    float* out_key = (float*)d_out;
    float* out_query = out_key + (size_t)BB * LL * D_MODEL;   // 2,097,152

    char* w8 = (char*)d_ws;
    auto alloc = [&](size_t bytes) {
        char* ptr = w8;
        w8 += (bytes + 255) & ~(size_t)255;
        return ptr;
    };
    float* zx     = (float*)alloc((size_t)8192 * 1024 * 4);
    float* bias10 = (float*)alloc((size_t)8192 * 10 * 4);
    float* S0q    = (float*)alloc((size_t)1200 * 512 * 4);
    float* dABb   = (float*)alloc((size_t)8192 * 8 * QP * 2 * 4);   // packed {dA,dtB}
    float* Cmb    = (float*)alloc((size_t)8192 * QP * 4);
    float* segd   = (float*)alloc((size_t)BB * NSEG * 8 * QP * 4);
    float* Sloc   = (float*)alloc((size_t)2 * NSEG * 32 * QP * 64 * 4);
    float* Sin    = (float*)alloc((size_t)2 * NSEG * 32 * QP * 64 * 4);
    float* yfb    = (float*)alloc((size_t)8192 * 512 * 4);
    float* ybb    = (float*)alloc((size_t)8192 * 512 * 4);
    float* Savg   = (float*)alloc((size_t)32 * QP * 64 * 4);
    ushort_t* ink_h  = (ushort_t*)alloc((size_t)2097152 * 2);
    ushort_t* ink_l  = (ushort_t*)alloc((size_t)2097152 * 2);
    ushort_t* wk_h   = (ushort_t*)alloc((size_t)262144 * 2);
    ushort_t* wk_l   = (ushort_t*)alloc((size_t)262144 * 2);
    ushort_t* inq_h  = (ushort_t*)alloc((size_t)307200 * 2);
    ushort_t* inq_l  = (ushort_t*)alloc((size_t)307200 * 2);
    ushort_t* wq_h   = (ushort_t*)alloc((size_t)131072 * 2);
    ushort_t* wq_l   = (ushort_t*)alloc((size_t)131072 * 2);
    ushort_t* keyb_h = (ushort_t*)alloc((size_t)4194304 * 2);
    ushort_t* keyb_l = (ushort_t*)alloc((size_t)4194304 * 2);
    ushort_t* wok_h  = (ushort_t*)alloc((size_t)131072 * 2);
    ushort_t* wok_l  = (ushort_t*)alloc((size_t)131072 * 2);
    ushort_t* lsn_h  = (ushort_t*)alloc((size_t)614400 * 2);
    ushort_t* lsn_l  = (ushort_t*)alloc((size_t)614400 * 2);
    ushort_t* woq_h  = (ushort_t*)alloc((size_t)131072 * 2);
    ushort_t* woq_l  = (ushort_t*)alloc((size_t)131072 * 2);

    // Input conversions (bf16 hi/lo)
    c_split<<<8192, 256, 0, stream>>>(in_key, ink_h, ink_l, 2097152);
    c_split<<<1024, 256, 0, stream>>>(W_key, wk_h, wk_l, 262144);       // rows 0..1023
    c_split<<<1200, 256, 0, stream>>>(in_query, inq_h, inq_l, 307200);
    c_split<<<512, 256, 0, stream>>>(W_query, wq_h, wq_l, 131072);
    c_split<<<512, 256, 0, stream>>>(W_out_key, wok_h, wok_l, 131072);
    c_split<<<512, 256, 0, stream>>>(W_out_query, woq_h, woq_l, 131072);

    // Projections
    gemm_bf16s<<<dim3(16, 64), 256, 0, stream>>>(ink_h, ink_l, wk_h, wk_l, zx, 8192, 1024, 256);
    k1b_bias<<<2048, 256, 0, stream>>>(in_key, W_key, bias10);
    gemm_bf16s<<<dim3(8, 10), 256, 0, stream>>>(inq_h, inq_l, wq_h, wq_l, S0q, 1200, 512, 256);

    // dist -> packed {dA,dtB}, Cm
    k2_dist<<<9600, 256, 0, stream>>>(dist, bias10, W_bc, W_dt, dt_bias, A_log, dABb, Cmb);

    // segmented bidirectional scan: march (also emits segd) + combine + MFMA corr
    pass_ac<<<dim3(NSEG, 32, 2), 256, 0, stream>>>(dABb, Cmb, zx, Sloc, segd, yfb, ybb);
    pass_b<<<2560, 256, 0, stream>>>(Sloc, segd, S0q, Sin, Savg);
    k3_corr<<<dim3(NSEG, 32, 2), 256, 0, stream>>>(dABb, Cmb, Sin, yfb, ybb);

    // out_key path (k4 writes split-bf16 directly)
    k4_gate<<<8192, 512, 0, stream>>>(yfb, ybb, zx, Dp, key_norm_w, keyb_h, keyb_l);
    gemm_bf16s<<<dim3(4, 64), 256, 0, stream>>>(keyb_h, keyb_l, wok_h, wok_l, out_key, 8192, 256, 512);

    // out_query path (k5 writes split-bf16 directly)
    k5_ln<<<1200, 512, 0, stream>>>(Savg, ln_w, ln_b, lsn_h, lsn_l);
    gemm_bf16s<<<dim3(4, 10), 256, 0, stream>>>(lsn_h, lsn_l, woq_h, woq_l, out_query, 1200, 256, 512);
}

// Round 7
// 902.127 us; speedup vs baseline: 1.0837x; 1.0337x over previous
//
#include <hip/hip_runtime.h>
#include <hip/hip_bf16.h>

// Problem constants
#define D_MODEL 256
#define D_INNER 512
#define NHEADS 8
#define HEADDIM 64
#define MDIST 16
#define BB 4
#define LL 2048
#define QQ 300
#define QP 320          // padded Q
#define NSEG 16
#define SEGLEN 128      // LL / NSEG

typedef unsigned short ushort_t;
typedef __attribute__((ext_vector_type(8))) short bf16x8;
typedef __attribute__((ext_vector_type(4))) float f32x4;
typedef __attribute__((ext_vector_type(2))) float f32x2;

__device__ __forceinline__ void bf16_split(float v, ushort_t& hi, ushort_t& lo) {
    __hip_bfloat16 h = __float2bfloat16(v);
    float hf = __bfloat162float(h);
    __hip_bfloat16 l = __float2bfloat16(v - hf);
    hi = *(ushort_t*)&h;
    lo = *(ushort_t*)&l;
}

__device__ __forceinline__ f32x2 shfl_xor2(f32x2 v, int m) {
    f32x2 r;
    r.x = __shfl_xor(v.x, m, 64);
    r.y = __shfl_xor(v.y, m, 64);
    return r;
}

// DPP cross-lane move (VALU pipe, NOT the shared DS pipe).
// quad_perm 0xB1 = xor1, 0x4E = xor2, 0x128 = row_ror:8 (xor8 within row of 16).
template<int CTRL>
__device__ __forceinline__ f32x2 dpp2(f32x2 v) {
    f32x2 r;
    r.x = __int_as_float(__builtin_amdgcn_update_dpp(0, __float_as_int(v.x), CTRL, 0xF, 0xF, true));
    r.y = __int_as_float(__builtin_amdgcn_update_dpp(0, __float_as_int(v.y), CTRL, 0xF, 0xF, true));
    return r;
}
// ds_swizzle xor patterns: 0x101F = xor4, 0x401F = xor16
template<int OFF>
__device__ __forceinline__ f32x2 swz2(f32x2 v) {
    f32x2 r;
    r.x = __int_as_float(__builtin_amdgcn_ds_swizzle(__float_as_int(v.x), OFF));
    r.y = __int_as_float(__builtin_amdgcn_ds_swizzle(__float_as_int(v.y), OFF));
    return r;
}

// ---------------------------------------------------------------------------
// Split fp32 -> bf16 hi + bf16 lo (residual). C = Ah*Bh + Ah*Bl + Al*Bh gives
// ~fp32 accuracy (missing Al*Bl term ~2^-18 relative).
// ---------------------------------------------------------------------------
__global__ __launch_bounds__(256) void c_split(const float* __restrict__ in,
                                               ushort_t* __restrict__ hi,
                                               ushort_t* __restrict__ lo, int n) {
    int i = blockIdx.x * 256 + threadIdx.x;
    if (i >= n) return;
    ushort_t h, l;
    bf16_split(in[i], h, l);
    hi[i] = h;
    lo[i] = l;
}

// ---------------------------------------------------------------------------
// Split-bf16 MFMA GEMM: C[M,N] = A[M,K] * B[N,K]^T (NT), fp32 out.
// ---------------------------------------------------------------------------
__global__ __launch_bounds__(256) void gemm_bf16s(const ushort_t* __restrict__ Ah,
                                                  const ushort_t* __restrict__ Al,
                                                  const ushort_t* __restrict__ Bh,
                                                  const ushort_t* __restrict__ Bl,
                                                  float* __restrict__ C,
                                                  int M, int N, int K) {
    int w = threadIdx.x >> 6, lane = threadIdx.x & 63;
    int n0 = blockIdx.x * 64;
    int m0 = blockIdx.y * 128 + w * 32;
    int lm = lane & 15, lk = (lane >> 4) * 8;
    f32x4 acc[2][4];
#pragma unroll
    for (int i = 0; i < 2; i++)
#pragma unroll
        for (int j = 0; j < 4; j++) acc[i][j] = {0.f, 0.f, 0.f, 0.f};

    for (int k0 = 0; k0 < K; k0 += 32) {
        bf16x8 ah[2], al[2], bh[4], blo[4];
#pragma unroll
        for (int mf = 0; mf < 2; mf++) {
            int row = m0 + mf * 16 + lm;
            if (row >= M) row = M - 1;            // safe clamp; epilogue guards
            size_t off = (size_t)row * K + k0 + lk;
            ah[mf] = *(const bf16x8*)(Ah + off);
            al[mf] = *(const bf16x8*)(Al + off);
        }
#pragma unroll
        for (int nf = 0; nf < 4; nf++) {
            int col = n0 + nf * 16 + lm;
            size_t off = (size_t)col * K + k0 + lk;
            bh[nf]  = *(const bf16x8*)(Bh + off);
            blo[nf] = *(const bf16x8*)(Bl + off);
        }
#pragma unroll
        for (int mf = 0; mf < 2; mf++)
#pragma unroll
            for (int nf = 0; nf < 4; nf++) {
                acc[mf][nf] = __builtin_amdgcn_mfma_f32_16x16x32_bf16(ah[mf], bh[nf],  acc[mf][nf], 0, 0, 0);
                acc[mf][nf] = __builtin_amdgcn_mfma_f32_16x16x32_bf16(ah[mf], blo[nf], acc[mf][nf], 0, 0, 0);
                acc[mf][nf] = __builtin_amdgcn_mfma_f32_16x16x32_bf16(al[mf], bh[nf],  acc[mf][nf], 0, 0, 0);
            }
    }
#pragma unroll
    for (int mf = 0; mf < 2; mf++)
#pragma unroll
        for (int nf = 0; nf < 4; nf++)
#pragma unroll
            for (int r = 0; r < 4; r++) {
                int m = m0 + mf * 16 + (lane >> 4) * 4 + r;
                if (m < M) C[(size_t)m * N + n0 + nf * 16 + lm] = acc[mf][nf][r];
            }
}

// ---------------------------------------------------------------------------
// K1b: fp32 bias columns (rows 1024..1033 of W_key) — precision-critical.
// ---------------------------------------------------------------------------
__global__ __launch_bounds__(256) void k1b_bias(const float* __restrict__ in_key,
                                                const float* __restrict__ W_key,
                                                float* __restrict__ bias10) {
    int w = threadIdx.x >> 6, lane = threadIdx.x & 63;
    int row = blockIdx.x * 4 + w;
    float4 a = *(const float4*)(in_key + (size_t)row * 256 + lane * 4);
#pragma unroll
    for (int c = 0; c < 10; c++) {
        float4 b = *(const float4*)(W_key + (size_t)(1024 + c) * 256 + lane * 4);
        float t = a.x * b.x + a.y * b.y + a.z * b.z + a.w * b.w;
#pragma unroll
        for (int o = 32; o > 0; o >>= 1) t += __shfl_down(t, o, 64);
        if (lane == 0) bias10[row * 10 + c] = t;
    }
}

// ---------------------------------------------------------------------------
// K2: dist (B,L,Q,16) -> dAB packed (pass_ac staging), dAd dense (k3_corr's
// full-sweep read — dense avoids the 2x fetch amplification of stride-2
// packed reads measured in R4/R6), Cm (B,L,QP).
// ---------------------------------------------------------------------------
__global__ __launch_bounds__(256) void k2_dist(const float* __restrict__ dist,
                                               const float* __restrict__ bias10,
                                               const float* __restrict__ W_bc,
                                               const float* __restrict__ W_dt,
                                               const float* __restrict__ dt_bias,
                                               const float* __restrict__ A_log,
                                               float* __restrict__ dAB,
                                               float* __restrict__ dAd,
                                               float* __restrict__ Cm) {
    __shared__ float sWbc[32], sWdt[128], sb[8], sA[8];
    int tid = threadIdx.x;
    if (tid < 32) sWbc[tid] = W_bc[tid];
    else if (tid < 160) sWdt[tid - 32] = W_dt[tid - 32];
    else if (tid < 168) sb[tid - 160] = dt_bias[tid - 160];
    else if (tid < 176) sA[tid - 168] = -expf(A_log[tid - 168]);
    __syncthreads();
    int gid = blockIdx.x * 256 + tid;          // (b*L + l)*Q + q
    if (gid >= BB * LL * QQ) return;
    int q = gid % QQ;
    int bl = gid / QQ;
    const float* dp = dist + (size_t)gid * 16;
    float d[16];
    float4 d0 = *(const float4*)(dp + 0);
    float4 d1 = *(const float4*)(dp + 4);
    float4 d2 = *(const float4*)(dp + 8);
    float4 d3 = *(const float4*)(dp + 12);
    d[0]=d0.x; d[1]=d0.y; d[2]=d0.z; d[3]=d0.w;
    d[4]=d1.x; d[5]=d1.y; d[6]=d1.z; d[7]=d1.w;
    d[8]=d2.x; d[9]=d2.y; d[10]=d2.z; d[11]=d2.w;
    d[12]=d3.x; d[13]=d3.y; d[14]=d3.z; d[15]=d3.w;
    float bc0 = 0.f, bc1 = 0.f;
#pragma unroll
    for (int m = 0; m < 16; m++) {
        bc0 = fmaf(d[m], sWbc[m], bc0);
        bc1 = fmaf(d[m], sWbc[16 + m], bc1);
    }
    float Bmv = bc0 + bias10[bl * 10 + 0];
    float Cv  = bc1 + bias10[bl * 10 + 1];
    Cm[bl * QP + q] = Cv;
#pragma unroll
    for (int h = 0; h < 8; h++) {
        float t = 0.f;
#pragma unroll
        for (int m = 0; m < 16; m++) t = fmaf(d[m], sWdt[h * 16 + m], t);
        float pre = t + bias10[bl * 10 + 2 + h] + sb[h];
        float dt = (pre > 20.f) ? pre : log1pf(expf(pre));
        int o = (bl * 8 + h) * QP + q;
        float2 v;
        v.x = expf(sA[h] * dt);      // dA
        v.y = dt * Bmv;              // dtB
        *(float2*)(dAB + (size_t)o * 2) = v;
        dAd[o] = v.x;
    }
}

// ---------------------------------------------------------------------------
// Pass AC (R4-measured 313 µs body, verbatim; + prodA/segd fusion):
// segment-local march (S_in = 0), computes S_local, y^loc AND segd (the
// segment decay product is order-independent, so any march order gives the
// same product; k2b kernel deleted). NO inline asm — R6 measured the asm
// pk variant at VGPR 112 / 378 µs vs the compiler's own codegen at 84/313.
//
// grid (NSEG, 32, 2), block 256 = 4 waves; wave w owns p in [16w, 16w+16),
// lane owns n in {64k+lane, k=0..4} -> S2[40] f32x2.
// G=4 LDS staging (32 KB, double-buffered), barrier per 4 steps.
// y-reduction: DPP quad_perm/row_ror on the VALU pipe; only xor4/xor16
// ds_swizzle + xor32 shfl touch the DS pipe.
// ---------------------------------------------------------------------------
__global__ __launch_bounds__(256) void pass_ac(const float* __restrict__ dAB,
                                               const float* __restrict__ Cm,
                                               const float* __restrict__ zx,
                                               float* __restrict__ S_local,
                                               float* __restrict__ segd,
                                               float* __restrict__ yf,
                                               float* __restrict__ yb) {
    __shared__ __align__(16) float sOp[2][4096];   // 32 KB: 4 steps x [ab 640 | c 320 | x 64]
    int seg = blockIdx.x, bh = blockIdx.y, dir = blockIdx.z;
    int tid = threadIdx.x;
    int w = tid >> 6, lane = tid & 63;
    int p0 = w * 16;
    int b = bh >> 3, h = bh & 7;
    f32x2 S2[40];                    // S2[k*8+j] <-> (n = 64k+lane, p = p0+2j+{0,1})
#pragma unroll
    for (int j = 0; j < 40; j++) S2[j] = {0.f, 0.f};
    float prodA[5];
#pragma unroll
    for (int k = 0; k < 5; k++) prodA[k] = 1.f;
    float* __restrict__ yo = dir ? yb : yf;
    bool s1 = (lane & 1) != 0, s2b = (lane & 2) != 0, s4 = (lane & 4) != 0;

    int pos = tid * 4;               // this thread's 4-float slice of each step
    auto stage = [&](int g, int buf) {
#pragma unroll
        for (int r = 0; r < 4; r++) {
            int i = g * 4 + r;
            int l = dir ? (LL - 1 - (seg * SEGLEN + i)) : (seg * SEGLEN + i);
            int bl = b * LL + l;
            const float* src;
            if (pos < 640)      src = dAB + (size_t)(bl * 8 + h) * 640 + pos;
            else if (pos < 960) src = Cm + (size_t)bl * QP + (pos - 640);
            else                src = zx + (size_t)bl * 1024 + 512 + h * 64 + (pos - 960);
            *(float4*)&sOp[buf][r * 1024 + pos] = *(const float4*)src;
        }
    };
    stage(0, 0);
    const int NGRP = SEGLEN / 4;          // 32 groups of 4 steps
    for (int g = 0; g < NGRP; g++) {
        __syncthreads();
        if (g + 1 < NGRP) stage(g + 1, (g + 1) & 1);
        const float* bufg = &sOp[g & 1][0];
#pragma unroll
        for (int it = 0; it < 4; it++) {
            const float* Bq = bufg + it * 1024;
            // x: wave-uniform 16 floats (broadcast b128 reads)
            float4 xq0 = *(const float4*)(Bq + 960 + p0);
            float4 xq1 = *(const float4*)(Bq + 964 + p0);
            float4 xq2 = *(const float4*)(Bq + 968 + p0);
            float4 xq3 = *(const float4*)(Bq + 972 + p0);
            f32x2 x2[8] = {{xq0.x, xq0.y}, {xq0.z, xq0.w}, {xq1.x, xq1.y}, {xq1.z, xq1.w},
                           {xq2.x, xq2.y}, {xq2.z, xq2.w}, {xq3.x, xq3.y}, {xq3.z, xq3.w}};
            f32x2 y[8];
#pragma unroll
            for (int j = 0; j < 8; j++) y[j] = {0.f, 0.f};
#pragma unroll
            for (int k = 0; k < 5; k++) {
                int n = k * 64 + lane;
                f32x2 ab = *(const f32x2*)(Bq + 2 * n);     // {dA, dtB}, b64 unique
                float c = Bq[640 + n];                      // b32 unique
                f32x2 a2 = {ab.x, ab.x}, b2 = {ab.y, ab.y}, c2 = {c, c};
                prodA[k] *= ab.x;
#pragma unroll
                for (int j = 0; j < 8; j++) {
                    f32x2 s = S2[k * 8 + j] * a2 + b2 * x2[j];
                    S2[k * 8 + j] = s;
                    y[j] += s * c2;
                }
            }
            // reduce-scatter 8 items over 64 lanes; final item (lane&7)
            // L1/L2: DPP quad_perm (VALU); L4: swizzle; L8: DPP ror; L16: swizzle; L32: shfl
            f32x2 u, v, z0, z1, z2, z3, w0, w1, q;
            u = s1 ? y[1] : y[0]; v = s1 ? y[0] : y[1]; z0 = u + dpp2<0xB1>(v);
            u = s1 ? y[3] : y[2]; v = s1 ? y[2] : y[3]; z1 = u + dpp2<0xB1>(v);
            u = s1 ? y[5] : y[4]; v = s1 ? y[4] : y[5]; z2 = u + dpp2<0xB1>(v);
            u = s1 ? y[7] : y[6]; v = s1 ? y[6] : y[7]; z3 = u + dpp2<0xB1>(v);
            u = s2b ? z1 : z0; v = s2b ? z0 : z1; w0 = u + dpp2<0x4E>(v);
            u = s2b ? z3 : z2; v = s2b ? z2 : z3; w1 = u + dpp2<0x4E>(v);
            u = s4 ? w1 : w0; v = s4 ? w0 : w1; q = u + swz2<0x101F>(v);
            q = q + dpp2<0x128>(q);       // xor8 (row_ror:8)
            q = q + swz2<0x401F>(q);      // xor16
            q = q + shfl_xor2(q, 32);     // xor32
            if (lane < 8) {
                int i = g * 4 + it;
                int l = dir ? (LL - 1 - (seg * SEGLEN + i)) : (seg * SEGLEN + i);
                int bl = b * LL + l;
                *(f32x2*)(yo + (size_t)(bl * 8 + h) * 64 + p0 + 2 * lane) = q;
            }
        }
    }
    // epilogue: store S_local (lane's 5 n-rows, 16 p's each)
    size_t base = (size_t)((dir * NSEG + seg) * 32 + bh) * QP * 64;
#pragma unroll
    for (int k = 0; k < 5; k++) {
        int n = k * 64 + lane;
#pragma unroll
        for (int t = 0; t < 4; t++) {
            float4 vv = {S2[k * 8 + 2 * t].x, S2[k * 8 + 2 * t].y,
                         S2[k * 8 + 2 * t + 1].x, S2[k * 8 + 2 * t + 1].y};
            *(float4*)&S_local[base + (size_t)n * 64 + p0 + 4 * t] = vv;
        }
    }
    // segd: product over the whole segment, order-independent -> dir0/w0 writes
    if (dir == 0 && w == 0) {
#pragma unroll
        for (int k = 0; k < 5; k++)
            segd[((b * NSEG + seg) * 8 + h) * QP + k * 64 + lane] = prodA[k];
    }
}

// ---------------------------------------------------------------------------
// Pass B: sequential segment combine (16 steps), writes S_in per segment and
// the averaged final state Savg (B,H,QP,P)
// ---------------------------------------------------------------------------
__global__ __launch_bounds__(256) void pass_b(const float* __restrict__ S_local,
                                              const float* __restrict__ segd,
                                              const float* __restrict__ S0q,
                                              float* __restrict__ S_in,
                                              float* __restrict__ Savg) {
    int gid = blockIdx.x * 256 + threadIdx.x;   // (b,h,n,p)
    if (gid >= BB * 8 * QP * 64) return;
    int p = gid & 63; int r = gid >> 6;
    int n = r % QP; r /= QP;
    int h = r & 7; int b = r >> 3;
    int bh = b * 8 + h;
    float s0 = (n < QQ) ? S0q[(size_t)(b * QQ + n) * 512 + h * 64 + p] : 0.f;
    float Sf = 0.f, Sb = 0.f;
    for (int dir = 0; dir < 2; dir++) {
        float S = s0;
        for (int s = 0; s < NSEG; s++) {
            size_t idx = (size_t)(((dir * NSEG + s) * 32 + bh) * QP + n) * 64 + p;
            S_in[idx] = S;
            int sf = dir ? (NSEG - 1 - s) : s;
            float dec = segd[((b * NSEG + sf) * 8 + h) * QP + n];
            S = fmaf(S, dec, S_local[idx]);
        }
        if (dir == 0) Sf = S; else Sb = S;
    }
    Savg[((bh) * QP + n) * 64 + p] = 0.5f * (Sf + Sb);
}

// ---------------------------------------------------------------------------
// K3_corr: y += Ahat @ S_in per (seg,bh,dir), where Ahat[i,n] = C_i[n] *
// cumprod_{k<=i} dA_k[n]. M=128 (steps), K=320 (n), N=64 (p).
// Reads the DENSE dA copy (dAd) — stride-1, no packed-layout amplification.
// ---------------------------------------------------------------------------
__global__ __launch_bounds__(256) void k3_corr(const float* __restrict__ dA,
                                               const float* __restrict__ Cm,
                                               const float* __restrict__ Sin,
                                               float* __restrict__ yf,
                                               float* __restrict__ yb) {
    __shared__ __align__(16) ushort_t sAh[128][48], sAl[128][48];  // 12 KB each
    __shared__ __align__(16) ushort_t sBh[64][48], sBl[64][48];    // 6 KB each
    __shared__ float pref[8][32];
    int seg = blockIdx.x, bh = blockIdx.y, dir = blockIdx.z;
    int b = bh >> 3, h = bh & 7;
    int tid = threadIdx.x;
    int w = tid >> 6, lane = tid & 63;
    int lm = lane & 15, lkq = lane >> 4;
    f32x4 acc[2][4];
#pragma unroll
    for (int i = 0; i < 2; i++)
#pragma unroll
        for (int j = 0; j < 4; j++) acc[i][j] = {0.f, 0.f, 0.f, 0.f};
    size_t sinBase = (size_t)((dir * NSEG + seg) * 32 + bh) * QP * 64;
    int nl = tid & 31, iseg = tid >> 5;   // cumprod roles: 32 n x 8 i-segments

    for (int k0 = 0; k0 < QP; k0 += 32) {
        __syncthreads();   // protect LDS reuse across chunks
        // ---- stage S_in chunk -> sB [p][k] split-bf16 ----
#pragma unroll
        for (int r = 0; r < 8; r++) {
            int flat = tid + r * 256;          // 0..2047
            int kn = flat >> 6, p = flat & 63;
            float v = Sin[sinBase + (size_t)(k0 + kn) * 64 + p];
            ushort_t hi, lo;
            bf16_split(v, hi, lo);
            sBh[p][kn] = hi;
            sBl[p][kn] = lo;
        }
        // ---- load dA/Cm for 16-step chain, local product ----
        float da[16], cm[16];
#pragma unroll
        for (int k = 0; k < 16; k++) {
            int i = iseg * 16 + k;
            int l = dir ? (LL - 1 - (seg * SEGLEN + i)) : (seg * SEGLEN + i);
            int bl = b * LL + l;
            da[k] = dA[(size_t)(bl * 8 + h) * QP + k0 + nl];
            cm[k] = Cm[(size_t)bl * QP + k0 + nl];
        }
        float lp = 1.f;
#pragma unroll
        for (int k = 0; k < 16; k++) lp *= da[k];
        pref[iseg][nl] = lp;
        __syncthreads();
        if (tid < 32) {                       // exclusive prefix over i-segments
            float c = 1.f;
#pragma unroll
            for (int s = 0; s < 8; s++) {
                float t = pref[s][tid];
                pref[s][tid] = c;
                c *= t;
            }
        }
        __syncthreads();
        float cum = pref[iseg][nl];
#pragma unroll
        for (int k = 0; k < 16; k++) {
            cum *= da[k];
            float v = cum * cm[k];
            ushort_t hi, lo;
            bf16_split(v, hi, lo);
            int i = iseg * 16 + k;
            sAh[i][nl] = hi;
            sAl[i][nl] = lo;
        }
        __syncthreads();
        // ---- MFMA ----
        bf16x8 ah[2], al[2], bhf[4], blf[4];
#pragma unroll
        for (int mf = 0; mf < 2; mf++) {
            int row = w * 32 + mf * 16 + lm;
            ah[mf] = *(const bf16x8*)&sAh[row][lkq * 8];
            al[mf] = *(const bf16x8*)&sAl[row][lkq * 8];
        }
#pragma unroll
        for (int nf = 0; nf < 4; nf++) {
            int p = nf * 16 + lm;
            bhf[nf] = *(const bf16x8*)&sBh[p][lkq * 8];
            blf[nf] = *(const bf16x8*)&sBl[p][lkq * 8];
        }
#pragma unroll
        for (int mf = 0; mf < 2; mf++)
#pragma unroll
            for (int nf = 0; nf < 4; nf++) {
                acc[mf][nf] = __builtin_amdgcn_mfma_f32_16x16x32_bf16(ah[mf], bhf[nf], acc[mf][nf], 0, 0, 0);
                acc[mf][nf] = __builtin_amdgcn_mfma_f32_16x16x32_bf16(ah[mf], blf[nf], acc[mf][nf], 0, 0, 0);
                acc[mf][nf] = __builtin_amdgcn_mfma_f32_16x16x32_bf16(al[mf], bhf[nf], acc[mf][nf], 0, 0, 0);
            }
    }
    // ---- epilogue: y += correction ----
    float* __restrict__ yo = dir ? yb : yf;
#pragma unroll
    for (int mf = 0; mf < 2; mf++)
#pragma unroll
        for (int nf = 0; nf < 4; nf++)
#pragma unroll
            for (int r = 0; r < 4; r++) {
                int i = w * 32 + mf * 16 + lkq * 4 + r;
                int p = nf * 16 + lm;
                int l = dir ? (LL - 1 - (seg * SEGLEN + i)) : (seg * SEGLEN + i);
                size_t idx = (size_t)((b * LL + l) * 8 + h) * 64 + p;
                yo[idx] += acc[mf][nf][r];
            }
}

// ---------------------------------------------------------------------------
// K4: y = 0.5*(yf+yb) + Dp*x ; g = y*silu(z) ; key = g * rms(g) * key_norm_w
// ---------------------------------------------------------------------------
__global__ __launch_bounds__(512) void k4_gate(const float* __restrict__ yf,
                                               const float* __restrict__ yb,
                                               const float* __restrict__ zx,
                                               const float* __restrict__ Dp,
                                               const float* __restrict__ knw,
                                               ushort_t* __restrict__ kh,
                                               ushort_t* __restrict__ kl) {
    int bl = blockIdx.x;
    int t = threadIdx.x;
    int h = t >> 6;
    float x = zx[(size_t)bl * 1024 + 512 + t];
    float yv = 0.5f * (yf[(size_t)bl * 512 + t] + yb[(size_t)bl * 512 + t]) + Dp[h] * x;
    float z = zx[(size_t)bl * 1024 + t];
    float g = yv * (z / (1.f + expf(-z)));
    float v = g * g;
#pragma unroll
    for (int o = 32; o > 0; o >>= 1) v += __shfl_down(v, o, 64);
    __shared__ float rs[8];
    __shared__ float stot;
    if ((t & 63) == 0) rs[t >> 6] = v;
    __syncthreads();
    if (t == 0) {
        float s = 0.f;
#pragma unroll
        for (int i = 0; i < 8; i++) s += rs[i];
        stot = s;
    }
    __syncthreads();
    float rms = rsqrtf(stot / 512.f + 1e-5f);
    float kv = g * rms * knw[t];
    ushort_t hi, lo;
    bf16_split(kv, hi, lo);
    kh[(size_t)bl * 512 + t] = hi;
    kl[(size_t)bl * 512 + t] = lo;
}

// ---------------------------------------------------------------------------
// K5: layernorm on Savg rearranged to (B,Q,512); one block per (b,q).
// ---------------------------------------------------------------------------
__global__ __launch_bounds__(512) void k5_ln(const float* __restrict__ Savg,
                                             const float* __restrict__ lnw,
                                             const float* __restrict__ lnb,
                                             ushort_t* __restrict__ lh,
                                             ushort_t* __restrict__ ll) {
    int bq = blockIdx.x;
    int b = bq / QQ, q = bq % QQ;
    int t = threadIdx.x;
    int h = t >> 6, p = t & 63;
    float v = Savg[((b * 8 + h) * QP + q) * 64 + p];
    float s1 = v, s2 = v * v;
#pragma unroll
    for (int o = 32; o > 0; o >>= 1) {
        s1 += __shfl_down(s1, o, 64);
        s2 += __shfl_down(s2, o, 64);
    }
    __shared__ float r1[8], r2[8];
    __shared__ float smu, srv;
    if ((t & 63) == 0) { r1[t >> 6] = s1; r2[t >> 6] = s2; }
    __syncthreads();
    if (t == 0) {
        float a = 0.f, c = 0.f;
#pragma unroll
        for (int i = 0; i < 8; i++) { a += r1[i]; c += r2[i]; }
        float mu = a / 512.f;
        float var = c / 512.f - mu * mu;
        smu = mu;
        srv = rsqrtf(var + 1e-5f);
    }
    __syncthreads();
    float ov = (v - smu) * srv * lnw[t] + lnb[t];
    ushort_t hi, lo;
    bf16_split(ov, hi, lo);
    lh[(size_t)bq * 512 + t] = hi;
    ll[(size_t)bq * 512 + t] = lo;
}

// ---------------------------------------------------------------------------
extern "C" void kernel_launch(void* const* d_in, const int* in_sizes, int n_in,
                              void* d_out, int out_size, void* d_ws, size_t ws_size,
                              hipStream_t stream) {
    const float* in_key    = (const float*)d_in[0];
    const float* in_query  = (const float*)d_in[1];
    const float* dist      = (const float*)d_in[2];
    const float* W_key     = (const float*)d_in[3];
    const float* W_query   = (const float*)d_in[4];
    const float* W_bc      = (const float*)d_in[5];
    const float* W_dt      = (const float*)d_in[6];
    const float* dt_bias   = (const float*)d_in[7];
    const float* A_log     = (const float*)d_in[8];
    const float* Dp        = (const float*)d_in[9];
    const float* W_out_key = (const float*)d_in[10];
    const float* W_out_query = (const float*)d_in[11];
    const float* key_norm_w = (const float*)d_in[12];
    const float* ln_w      = (const float*)d_in[13];
    const float* ln_b      = (const float*)d_in[14];

    float* out_key = (float*)d_out;
    float* out_query = out_key + (size_t)BB * LL * D_MODEL;   // 2,097,152

    char* w8 = (char*)d_ws;
    auto alloc = [&](size_t bytes) {
        char* ptr = w8;
        w8 += (bytes + 255) & ~(size_t)255;
        return ptr;
    };
    float* zx     = (float*)alloc((size_t)8192 * 1024 * 4);
    float* bias10 = (float*)alloc((size_t)8192 * 10 * 4);
    float* S0q    = (float*)alloc((size_t)1200 * 512 * 4);
    float* dABb   = (float*)alloc((size_t)8192 * 8 * QP * 2 * 4);   // packed {dA,dtB}
    float* dAd    = (float*)alloc((size_t)8192 * 8 * QP * 4);       // dense dA (k3_corr)
    float* Cmb    = (float*)alloc((size_t)8192 * QP * 4);
    float* segd   = (float*)alloc((size_t)BB * NSEG * 8 * QP * 4);
    float* Sloc   = (float*)alloc((size_t)2 * NSEG * 32 * QP * 64 * 4);
    float* Sin    = (float*)alloc((size_t)2 * NSEG * 32 * QP * 64 * 4);
    float* yfb    = (float*)alloc((size_t)8192 * 512 * 4);
    float* ybb    = (float*)alloc((size_t)8192 * 512 * 4);
    float* Savg   = (float*)alloc((size_t)32 * QP * 64 * 4);
    ushort_t* ink_h  = (ushort_t*)alloc((size_t)2097152 * 2);
    ushort_t* ink_l  = (ushort_t*)alloc((size_t)2097152 * 2);
    ushort_t* wk_h   = (ushort_t*)alloc((size_t)262144 * 2);
    ushort_t* wk_l   = (ushort_t*)alloc((size_t)262144 * 2);
    ushort_t* inq_h  = (ushort_t*)alloc((size_t)307200 * 2);
    ushort_t* inq_l  = (ushort_t*)alloc((size_t)307200 * 2);
    ushort_t* wq_h   = (ushort_t*)alloc((size_t)131072 * 2);
    ushort_t* wq_l   = (ushort_t*)alloc((size_t)131072 * 2);
    ushort_t* keyb_h = (ushort_t*)alloc((size_t)4194304 * 2);
    ushort_t* keyb_l = (ushort_t*)alloc((size_t)4194304 * 2);
    ushort_t* wok_h  = (ushort_t*)alloc((size_t)131072 * 2);
    ushort_t* wok_l  = (ushort_t*)alloc((size_t)131072 * 2);
    ushort_t* lsn_h  = (ushort_t*)alloc((size_t)614400 * 2);
    ushort_t* lsn_l  = (ushort_t*)alloc((size_t)614400 * 2);
    ushort_t* woq_h  = (ushort_t*)alloc((size_t)131072 * 2);
    ushort_t* woq_l  = (ushort_t*)alloc((size_t)131072 * 2);

    // Input conversions (bf16 hi/lo)
    c_split<<<8192, 256, 0, stream>>>(in_key, ink_h, ink_l, 2097152);
    c_split<<<1024, 256, 0, stream>>>(W_key, wk_h, wk_l, 262144);       // rows 0..1023
    c_split<<<1200, 256, 0, stream>>>(in_query, inq_h, inq_l, 307200);
    c_split<<<512, 256, 0, stream>>>(W_query, wq_h, wq_l, 131072);
    c_split<<<512, 256, 0, stream>>>(W_out_key, wok_h, wok_l, 131072);
    c_split<<<512, 256, 0, stream>>>(W_out_query, woq_h, woq_l, 131072);

    // Projections
    gemm_bf16s<<<dim3(16, 64), 256, 0, stream>>>(ink_h, ink_l, wk_h, wk_l, zx, 8192, 1024, 256);
    k1b_bias<<<2048, 256, 0, stream>>>(in_key, W_key, bias10);
    gemm_bf16s<<<dim3(8, 10), 256, 0, stream>>>(inq_h, inq_l, wq_h, wq_l, S0q, 1200, 512, 256);

    // dist -> packed {dA,dtB} + dense dA + Cm
    k2_dist<<<9600, 256, 0, stream>>>(dist, bias10, W_bc, W_dt, dt_bias, A_log, dABb, dAd, Cmb);

    // segmented bidirectional scan: march (also emits segd) + combine + MFMA corr
    pass_ac<<<dim3(NSEG, 32, 2), 256, 0, stream>>>(dABb, Cmb, zx, Sloc, segd, yfb, ybb);
    pass_b<<<2560, 256, 0, stream>>>(Sloc, segd, S0q, Sin, Savg);
    k3_corr<<<dim3(NSEG, 32, 2), 256, 0, stream>>>(dAd, Cmb, Sin, yfb, ybb);

    // out_key path (k4 writes split-bf16 directly)
    k4_gate<<<8192, 512, 0, stream>>>(yfb, ybb, zx, Dp, key_norm_w, keyb_h, keyb_l);
    gemm_bf16s<<<dim3(4, 64), 256, 0, stream>>>(keyb_h, keyb_l, wok_h, wok_l, out_key, 8192, 256, 512);

    // out_query path (k5 writes split-bf16 directly)
    k5_ln<<<1200, 512, 0, stream>>>(Savg, ln_w, ln_b, lsn_h, lsn_l);
    gemm_bf16s<<<dim3(4, 10), 256, 0, stream>>>(lsn_h, lsn_l, woq_h, woq_l, out_query, 1200, 256, 512);
}

// Round 8
// 894.215 us; speedup vs baseline: 1.0933x; 1.0088x over previous
//
#include <hip/hip_runtime.h>
#include <hip/hip_bf16.h>

// Problem constants
#define D_MODEL 256
#define D_INNER 512
#define NHEADS 8
#define HEADDIM 64
#define MDIST 16
#define BB 4
#define LL 2048
#define QQ 300
#define QP 320          // padded Q
#define NSEG 16
#define SEGLEN 128      // LL / NSEG

typedef unsigned short ushort_t;
typedef __attribute__((ext_vector_type(8))) short bf16x8;
typedef __attribute__((ext_vector_type(4))) float f32x4;
typedef __attribute__((ext_vector_type(2))) float f32x2;

__device__ __forceinline__ void bf16_split(float v, ushort_t& hi, ushort_t& lo) {
    __hip_bfloat16 h = __float2bfloat16(v);
    float hf = __bfloat162float(h);
    __hip_bfloat16 l = __float2bfloat16(v - hf);
    hi = *(ushort_t*)&h;
    lo = *(ushort_t*)&l;
}

__device__ __forceinline__ f32x2 shfl_xor2(f32x2 v, int m) {
    f32x2 r;
    r.x = __shfl_xor(v.x, m, 64);
    r.y = __shfl_xor(v.y, m, 64);
    return r;
}

// DPP cross-lane move (VALU pipe, NOT the shared DS pipe).
// quad_perm 0xB1 = xor1, 0x4E = xor2, 0x128 = row_ror:8 (xor8 within row of 16).
template<int CTRL>
__device__ __forceinline__ f32x2 dpp2(f32x2 v) {
    f32x2 r;
    r.x = __int_as_float(__builtin_amdgcn_update_dpp(0, __float_as_int(v.x), CTRL, 0xF, 0xF, true));
    r.y = __int_as_float(__builtin_amdgcn_update_dpp(0, __float_as_int(v.y), CTRL, 0xF, 0xF, true));
    return r;
}
// ds_swizzle xor patterns: 0x101F = xor4, 0x401F = xor16
template<int OFF>
__device__ __forceinline__ f32x2 swz2(f32x2 v) {
    f32x2 r;
    r.x = __int_as_float(__builtin_amdgcn_ds_swizzle(__float_as_int(v.x), OFF));
    r.y = __int_as_float(__builtin_amdgcn_ds_swizzle(__float_as_int(v.y), OFF));
    return r;
}

// ---------------------------------------------------------------------------
// Split fp32 -> bf16 hi + bf16 lo (residual). C = Ah*Bh + Ah*Bl + Al*Bh gives
// ~fp32 accuracy (missing Al*Bl term ~2^-18 relative).
// ---------------------------------------------------------------------------
__global__ __launch_bounds__(256) void c_split(const float* __restrict__ in,
                                               ushort_t* __restrict__ hi,
                                               ushort_t* __restrict__ lo, int n) {
    int i = blockIdx.x * 256 + threadIdx.x;
    if (i >= n) return;
    ushort_t h, l;
    bf16_split(in[i], h, l);
    hi[i] = h;
    lo[i] = l;
}

// ---------------------------------------------------------------------------
// Split-bf16 MFMA GEMM: C[M,N] = A[M,K] * B[N,K]^T (NT), fp32 out.
// ---------------------------------------------------------------------------
__global__ __launch_bounds__(256) void gemm_bf16s(const ushort_t* __restrict__ Ah,
                                                  const ushort_t* __restrict__ Al,
                                                  const ushort_t* __restrict__ Bh,
                                                  const ushort_t* __restrict__ Bl,
                                                  float* __restrict__ C,
                                                  int M, int N, int K) {
    int w = threadIdx.x >> 6, lane = threadIdx.x & 63;
    int n0 = blockIdx.x * 64;
    int m0 = blockIdx.y * 128 + w * 32;
    int lm = lane & 15, lk = (lane >> 4) * 8;
    f32x4 acc[2][4];
#pragma unroll
    for (int i = 0; i < 2; i++)
#pragma unroll
        for (int j = 0; j < 4; j++) acc[i][j] = {0.f, 0.f, 0.f, 0.f};

    for (int k0 = 0; k0 < K; k0 += 32) {
        bf16x8 ah[2], al[2], bh[4], blo[4];
#pragma unroll
        for (int mf = 0; mf < 2; mf++) {
            int row = m0 + mf * 16 + lm;
            if (row >= M) row = M - 1;            // safe clamp; epilogue guards
            size_t off = (size_t)row * K + k0 + lk;
            ah[mf] = *(const bf16x8*)(Ah + off);
            al[mf] = *(const bf16x8*)(Al + off);
        }
#pragma unroll
        for (int nf = 0; nf < 4; nf++) {
            int col = n0 + nf * 16 + lm;
            size_t off = (size_t)col * K + k0 + lk;
            bh[nf]  = *(const bf16x8*)(Bh + off);
            blo[nf] = *(const bf16x8*)(Bl + off);
        }
#pragma unroll
        for (int mf = 0; mf < 2; mf++)
#pragma unroll
            for (int nf = 0; nf < 4; nf++) {
                acc[mf][nf] = __builtin_amdgcn_mfma_f32_16x16x32_bf16(ah[mf], bh[nf],  acc[mf][nf], 0, 0, 0);
                acc[mf][nf] = __builtin_amdgcn_mfma_f32_16x16x32_bf16(ah[mf], blo[nf], acc[mf][nf], 0, 0, 0);
                acc[mf][nf] = __builtin_amdgcn_mfma_f32_16x16x32_bf16(al[mf], bh[nf],  acc[mf][nf], 0, 0, 0);
            }
    }
#pragma unroll
    for (int mf = 0; mf < 2; mf++)
#pragma unroll
        for (int nf = 0; nf < 4; nf++)
#pragma unroll
            for (int r = 0; r < 4; r++) {
                int m = m0 + mf * 16 + (lane >> 4) * 4 + r;
                if (m < M) C[(size_t)m * N + n0 + nf * 16 + lm] = acc[mf][nf][r];
            }
}

// ---------------------------------------------------------------------------
// K1b: fp32 bias columns (rows 1024..1033 of W_key) — precision-critical.
// ---------------------------------------------------------------------------
__global__ __launch_bounds__(256) void k1b_bias(const float* __restrict__ in_key,
                                                const float* __restrict__ W_key,
                                                float* __restrict__ bias10) {
    int w = threadIdx.x >> 6, lane = threadIdx.x & 63;
    int row = blockIdx.x * 4 + w;
    float4 a = *(const float4*)(in_key + (size_t)row * 256 + lane * 4);
#pragma unroll
    for (int c = 0; c < 10; c++) {
        float4 b = *(const float4*)(W_key + (size_t)(1024 + c) * 256 + lane * 4);
        float t = a.x * b.x + a.y * b.y + a.z * b.z + a.w * b.w;
#pragma unroll
        for (int o = 32; o > 0; o >>= 1) t += __shfl_down(t, o, 64);
        if (lane == 0) bias10[row * 10 + c] = t;
    }
}

// ---------------------------------------------------------------------------
// K2: dist (B,L,Q,16) -> dAB packed (pass_ac staging), dAd dense (k2b +
// k3_corr full-sweep reads — dense avoids the 2x fetch amplification of
// stride-2 packed reads measured in R4/R6), Cm (B,L,QP).
// ---------------------------------------------------------------------------
__global__ __launch_bounds__(256) void k2_dist(const float* __restrict__ dist,
                                               const float* __restrict__ bias10,
                                               const float* __restrict__ W_bc,
                                               const float* __restrict__ W_dt,
                                               const float* __restrict__ dt_bias,
                                               const float* __restrict__ A_log,
                                               float* __restrict__ dAB,
                                               float* __restrict__ dAd,
                                               float* __restrict__ Cm) {
    __shared__ float sWbc[32], sWdt[128], sb[8], sA[8];
    int tid = threadIdx.x;
    if (tid < 32) sWbc[tid] = W_bc[tid];
    else if (tid < 160) sWdt[tid - 32] = W_dt[tid - 32];
    else if (tid < 168) sb[tid - 160] = dt_bias[tid - 160];
    else if (tid < 176) sA[tid - 168] = -expf(A_log[tid - 168]);
    __syncthreads();
    int gid = blockIdx.x * 256 + tid;          // (b*L + l)*Q + q
    if (gid >= BB * LL * QQ) return;
    int q = gid % QQ;
    int bl = gid / QQ;
    const float* dp = dist + (size_t)gid * 16;
    float d[16];
    float4 d0 = *(const float4*)(dp + 0);
    float4 d1 = *(const float4*)(dp + 4);
    float4 d2 = *(const float4*)(dp + 8);
    float4 d3 = *(const float4*)(dp + 12);
    d[0]=d0.x; d[1]=d0.y; d[2]=d0.z; d[3]=d0.w;
    d[4]=d1.x; d[5]=d1.y; d[6]=d1.z; d[7]=d1.w;
    d[8]=d2.x; d[9]=d2.y; d[10]=d2.z; d[11]=d2.w;
    d[12]=d3.x; d[13]=d3.y; d[14]=d3.z; d[15]=d3.w;
    float bc0 = 0.f, bc1 = 0.f;
#pragma unroll
    for (int m = 0; m < 16; m++) {
        bc0 = fmaf(d[m], sWbc[m], bc0);
        bc1 = fmaf(d[m], sWbc[16 + m], bc1);
    }
    float Bmv = bc0 + bias10[bl * 10 + 0];
    float Cv  = bc1 + bias10[bl * 10 + 1];
    Cm[bl * QP + q] = Cv;
#pragma unroll
    for (int h = 0; h < 8; h++) {
        float t = 0.f;
#pragma unroll
        for (int m = 0; m < 16; m++) t = fmaf(d[m], sWdt[h * 16 + m], t);
        float pre = t + bias10[bl * 10 + 2 + h] + sb[h];
        float dt = (pre > 20.f) ? pre : log1pf(expf(pre));
        int o = (bl * 8 + h) * QP + q;
        float2 v;
        v.x = expf(sA[h] * dt);      // dA
        v.y = dt * Bmv;              // dtB
        *(float2*)(dAB + (size_t)o * 2) = v;
        dAd[o] = v.x;
    }
}

// ---------------------------------------------------------------------------
// K2b: per-segment decay product segd (B,NSEG,H,QP). Reads DENSE dAd
// (stride-1 across lanes per iteration; ~84 MB total -> BW-bound ~15-25 µs).
// Reinstated: fusing this product into pass_ac cost +16 VGPR / +56 µs (R7),
// more than the kernel itself costs.
// ---------------------------------------------------------------------------
__global__ __launch_bounds__(256) void k2b_segdecay(const float* __restrict__ dA,
                                                    float* __restrict__ segd) {
    int gid = blockIdx.x * 256 + threadIdx.x;   // ((b*16+s)*8+h)*QP+q
    if (gid >= BB * NSEG * 8 * QP) return;
    int q = gid % QP; int r = gid / QP;
    int h = r % 8; r /= 8;
    int s = r % NSEG; int b = r / NSEG;
    size_t base = (size_t)((b * LL + s * SEGLEN) * 8 + h) * QP + q;
    float p = 1.f;
    for (int i = 0; i < SEGLEN; i++) p *= dA[base + (size_t)i * 8 * QP];
    segd[gid] = p;
}

// ---------------------------------------------------------------------------
// Pass AC (exact R4-measured body: 313 µs, VGPR 84, Occ 25%):
// segment-local march (S_in = 0), computes S_local AND y^loc.
// grid (NSEG, 32, 2), block 256 = 4 waves; wave w owns p in [16w, 16w+16),
// lane owns n in {64k+lane, k=0..4} -> S2[40] f32x2.
// G=4 LDS staging (32 KB, double-buffered), barrier per 4 steps.
// y-reduction: DPP quad_perm/row_ror on the VALU pipe; only xor4/xor16
// ds_swizzle + xor32 shfl touch the DS pipe.
// NO prodA fusion (R7: +16 VGPR, -4% occ, +56 µs) and NO inline-asm pk
// (R6: +28 VGPR, +65 µs) — both measured regressions on this body.
// ---------------------------------------------------------------------------
__global__ __launch_bounds__(256) void pass_ac(const float* __restrict__ dAB,
                                               const float* __restrict__ Cm,
                                               const float* __restrict__ zx,
                                               float* __restrict__ S_local,
                                               float* __restrict__ yf,
                                               float* __restrict__ yb) {
    __shared__ __align__(16) float sOp[2][4096];   // 32 KB: 4 steps x [ab 640 | c 320 | x 64]
    int seg = blockIdx.x, bh = blockIdx.y, dir = blockIdx.z;
    int tid = threadIdx.x;
    int w = tid >> 6, lane = tid & 63;
    int p0 = w * 16;
    int b = bh >> 3, h = bh & 7;
    f32x2 S2[40];                    // S2[k*8+j] <-> (n = 64k+lane, p = p0+2j+{0,1})
#pragma unroll
    for (int j = 0; j < 40; j++) S2[j] = {0.f, 0.f};
    float* __restrict__ yo = dir ? yb : yf;
    bool s1 = (lane & 1) != 0, s2b = (lane & 2) != 0, s4 = (lane & 4) != 0;

    int pos = tid * 4;               // this thread's 4-float slice of each step
    auto stage = [&](int g, int buf) {
#pragma unroll
        for (int r = 0; r < 4; r++) {
            int i = g * 4 + r;
            int l = dir ? (LL - 1 - (seg * SEGLEN + i)) : (seg * SEGLEN + i);
            int bl = b * LL + l;
            const float* src;
            if (pos < 640)      src = dAB + (size_t)(bl * 8 + h) * 640 + pos;
            else if (pos < 960) src = Cm + (size_t)bl * QP + (pos - 640);
            else                src = zx + (size_t)bl * 1024 + 512 + h * 64 + (pos - 960);
            *(float4*)&sOp[buf][r * 1024 + pos] = *(const float4*)src;
        }
    };
    stage(0, 0);
    const int NGRP = SEGLEN / 4;          // 32 groups of 4 steps
    for (int g = 0; g < NGRP; g++) {
        __syncthreads();
        if (g + 1 < NGRP) stage(g + 1, (g + 1) & 1);
        const float* bufg = &sOp[g & 1][0];
#pragma unroll
        for (int it = 0; it < 4; it++) {
            const float* Bq = bufg + it * 1024;
            // x: wave-uniform 16 floats (broadcast b128 reads)
            float4 xq0 = *(const float4*)(Bq + 960 + p0);
            float4 xq1 = *(const float4*)(Bq + 964 + p0);
            float4 xq2 = *(const float4*)(Bq + 968 + p0);
            float4 xq3 = *(const float4*)(Bq + 972 + p0);
            f32x2 x2[8] = {{xq0.x, xq0.y}, {xq0.z, xq0.w}, {xq1.x, xq1.y}, {xq1.z, xq1.w},
                           {xq2.x, xq2.y}, {xq2.z, xq2.w}, {xq3.x, xq3.y}, {xq3.z, xq3.w}};
            f32x2 y[8];
#pragma unroll
            for (int j = 0; j < 8; j++) y[j] = {0.f, 0.f};
#pragma unroll
            for (int k = 0; k < 5; k++) {
                int n = k * 64 + lane;
                f32x2 ab = *(const f32x2*)(Bq + 2 * n);     // {dA, dtB}, b64 unique
                float c = Bq[640 + n];                      // b32 unique
                f32x2 a2 = {ab.x, ab.x}, b2 = {ab.y, ab.y}, c2 = {c, c};
#pragma unroll
                for (int j = 0; j < 8; j++) {
                    f32x2 s = S2[k * 8 + j] * a2 + b2 * x2[j];
                    S2[k * 8 + j] = s;
                    y[j] += s * c2;
                }
            }
            // reduce-scatter 8 items over 64 lanes; final item (lane&7)
            // L1/L2: DPP quad_perm (VALU); L4: swizzle; L8: DPP ror; L16: swizzle; L32: shfl
            f32x2 u, v, z0, z1, z2, z3, w0, w1, q;
            u = s1 ? y[1] : y[0]; v = s1 ? y[0] : y[1]; z0 = u + dpp2<0xB1>(v);
            u = s1 ? y[3] : y[2]; v = s1 ? y[2] : y[3]; z1 = u + dpp2<0xB1>(v);
            u = s1 ? y[5] : y[4]; v = s1 ? y[4] : y[5]; z2 = u + dpp2<0xB1>(v);
            u = s1 ? y[7] : y[6]; v = s1 ? y[6] : y[7]; z3 = u + dpp2<0xB1>(v);
            u = s2b ? z1 : z0; v = s2b ? z0 : z1; w0 = u + dpp2<0x4E>(v);
            u = s2b ? z3 : z2; v = s2b ? z2 : z3; w1 = u + dpp2<0x4E>(v);
            u = s4 ? w1 : w0; v = s4 ? w0 : w1; q = u + swz2<0x101F>(v);
            q = q + dpp2<0x128>(q);       // xor8 (row_ror:8)
            q = q + swz2<0x401F>(q);      // xor16
            q = q + shfl_xor2(q, 32);     // xor32
            if (lane < 8) {
                int i = g * 4 + it;
                int l = dir ? (LL - 1 - (seg * SEGLEN + i)) : (seg * SEGLEN + i);
                int bl = b * LL + l;
                *(f32x2*)(yo + (size_t)(bl * 8 + h) * 64 + p0 + 2 * lane) = q;
            }
        }
    }
    // epilogue: store S_local (lane's 5 n-rows, 16 p's each)
    size_t base = (size_t)((dir * NSEG + seg) * 32 + bh) * QP * 64;
#pragma unroll
    for (int k = 0; k < 5; k++) {
        int n = k * 64 + lane;
#pragma unroll
        for (int t = 0; t < 4; t++) {
            float4 vv = {S2[k * 8 + 2 * t].x, S2[k * 8 + 2 * t].y,
                         S2[k * 8 + 2 * t + 1].x, S2[k * 8 + 2 * t + 1].y};
            *(float4*)&S_local[base + (size_t)n * 64 + p0 + 4 * t] = vv;
        }
    }
}

// ---------------------------------------------------------------------------
// Pass B: sequential segment combine (16 steps), writes S_in per segment and
// the averaged final state Savg (B,H,QP,P)
// ---------------------------------------------------------------------------
__global__ __launch_bounds__(256) void pass_b(const float* __restrict__ S_local,
                                              const float* __restrict__ segd,
                                              const float* __restrict__ S0q,
                                              float* __restrict__ S_in,
                                              float* __restrict__ Savg) {
    int gid = blockIdx.x * 256 + threadIdx.x;   // (b,h,n,p)
    if (gid >= BB * 8 * QP * 64) return;
    int p = gid & 63; int r = gid >> 6;
    int n = r % QP; r /= QP;
    int h = r & 7; int b = r >> 3;
    int bh = b * 8 + h;
    float s0 = (n < QQ) ? S0q[(size_t)(b * QQ + n) * 512 + h * 64 + p] : 0.f;
    float Sf = 0.f, Sb = 0.f;
    for (int dir = 0; dir < 2; dir++) {
        float S = s0;
        for (int s = 0; s < NSEG; s++) {
            size_t idx = (size_t)(((dir * NSEG + s) * 32 + bh) * QP + n) * 64 + p;
            S_in[idx] = S;
            int sf = dir ? (NSEG - 1 - s) : s;
            float dec = segd[((b * NSEG + sf) * 8 + h) * QP + n];
            S = fmaf(S, dec, S_local[idx]);
        }
        if (dir == 0) Sf = S; else Sb = S;
    }
    Savg[((bh) * QP + n) * 64 + p] = 0.5f * (Sf + Sb);
}

// ---------------------------------------------------------------------------
// K3_corr: y += Ahat @ S_in per (seg,bh,dir), where Ahat[i,n] = C_i[n] *
// cumprod_{k<=i} dA_k[n]. M=128 (steps), K=320 (n), N=64 (p).
// Reads the DENSE dA copy (dAd) — stride-1, no packed-layout amplification.
// ---------------------------------------------------------------------------
__global__ __launch_bounds__(256) void k3_corr(const float* __restrict__ dA,
                                               const float* __restrict__ Cm,
                                               const float* __restrict__ Sin,
                                               float* __restrict__ yf,
                                               float* __restrict__ yb) {
    __shared__ __align__(16) ushort_t sAh[128][48], sAl[128][48];  // 12 KB each
    __shared__ __align__(16) ushort_t sBh[64][48], sBl[64][48];    // 6 KB each
    __shared__ float pref[8][32];
    int seg = blockIdx.x, bh = blockIdx.y, dir = blockIdx.z;
    int b = bh >> 3, h = bh & 7;
    int tid = threadIdx.x;
    int w = tid >> 6, lane = tid & 63;
    int lm = lane & 15, lkq = lane >> 4;
    f32x4 acc[2][4];
#pragma unroll
    for (int i = 0; i < 2; i++)
#pragma unroll
        for (int j = 0; j < 4; j++) acc[i][j] = {0.f, 0.f, 0.f, 0.f};
    size_t sinBase = (size_t)((dir * NSEG + seg) * 32 + bh) * QP * 64;
    int nl = tid & 31, iseg = tid >> 5;   // cumprod roles: 32 n x 8 i-segments

    for (int k0 = 0; k0 < QP; k0 += 32) {
        __syncthreads();   // protect LDS reuse across chunks
        // ---- stage S_in chunk -> sB [p][k] split-bf16 ----
#pragma unroll
        for (int r = 0; r < 8; r++) {
            int flat = tid + r * 256;          // 0..2047
            int kn = flat >> 6, p = flat & 63;
            float v = Sin[sinBase + (size_t)(k0 + kn) * 64 + p];
            ushort_t hi, lo;
            bf16_split(v, hi, lo);
            sBh[p][kn] = hi;
            sBl[p][kn] = lo;
        }
        // ---- load dA/Cm for 16-step chain, local product ----
        float da[16], cm[16];
#pragma unroll
        for (int k = 0; k < 16; k++) {
            int i = iseg * 16 + k;
            int l = dir ? (LL - 1 - (seg * SEGLEN + i)) : (seg * SEGLEN + i);
            int bl = b * LL + l;
            da[k] = dA[(size_t)(bl * 8 + h) * QP + k0 + nl];
            cm[k] = Cm[(size_t)bl * QP + k0 + nl];
        }
        float lp = 1.f;
#pragma unroll
        for (int k = 0; k < 16; k++) lp *= da[k];
        pref[iseg][nl] = lp;
        __syncthreads();
        if (tid < 32) {                       // exclusive prefix over i-segments
            float c = 1.f;
#pragma unroll
            for (int s = 0; s < 8; s++) {
                float t = pref[s][tid];
                pref[s][tid] = c;
                c *= t;
            }
        }
        __syncthreads();
        float cum = pref[iseg][nl];
#pragma unroll
        for (int k = 0; k < 16; k++) {
            cum *= da[k];
            float v = cum * cm[k];
            ushort_t hi, lo;
            bf16_split(v, hi, lo);
            int i = iseg * 16 + k;
            sAh[i][nl] = hi;
            sAl[i][nl] = lo;
        }
        __syncthreads();
        // ---- MFMA ----
        bf16x8 ah[2], al[2], bhf[4], blf[4];
#pragma unroll
        for (int mf = 0; mf < 2; mf++) {
            int row = w * 32 + mf * 16 + lm;
            ah[mf] = *(const bf16x8*)&sAh[row][lkq * 8];
            al[mf] = *(const bf16x8*)&sAl[row][lkq * 8];
        }
#pragma unroll
        for (int nf = 0; nf < 4; nf++) {
            int p = nf * 16 + lm;
            bhf[nf] = *(const bf16x8*)&sBh[p][lkq * 8];
            blf[nf] = *(const bf16x8*)&sBl[p][lkq * 8];
        }
#pragma unroll
        for (int mf = 0; mf < 2; mf++)
#pragma unroll
            for (int nf = 0; nf < 4; nf++) {
                acc[mf][nf] = __builtin_amdgcn_mfma_f32_16x16x32_bf16(ah[mf], bhf[nf], acc[mf][nf], 0, 0, 0);
                acc[mf][nf] = __builtin_amdgcn_mfma_f32_16x16x32_bf16(ah[mf], blf[nf], acc[mf][nf], 0, 0, 0);
                acc[mf][nf] = __builtin_amdgcn_mfma_f32_16x16x32_bf16(al[mf], bhf[nf], acc[mf][nf], 0, 0, 0);
            }
    }
    // ---- epilogue: y += correction ----
    float* __restrict__ yo = dir ? yb : yf;
#pragma unroll
    for (int mf = 0; mf < 2; mf++)
#pragma unroll
        for (int nf = 0; nf < 4; nf++)
#pragma unroll
            for (int r = 0; r < 4; r++) {
                int i = w * 32 + mf * 16 + lkq * 4 + r;
                int p = nf * 16 + lm;
                int l = dir ? (LL - 1 - (seg * SEGLEN + i)) : (seg * SEGLEN + i);
                size_t idx = (size_t)((b * LL + l) * 8 + h) * 64 + p;
                yo[idx] += acc[mf][nf][r];
            }
}

// ---------------------------------------------------------------------------
// K4: y = 0.5*(yf+yb) + Dp*x ; g = y*silu(z) ; key = g * rms(g) * key_norm_w
// ---------------------------------------------------------------------------
__global__ __launch_bounds__(512) void k4_gate(const float* __restrict__ yf,
                                               const float* __restrict__ yb,
                                               const float* __restrict__ zx,
                                               const float* __restrict__ Dp,
                                               const float* __restrict__ knw,
                                               ushort_t* __restrict__ kh,
                                               ushort_t* __restrict__ kl) {
    int bl = blockIdx.x;
    int t = threadIdx.x;
    int h = t >> 6;
    float x = zx[(size_t)bl * 1024 + 512 + t];
    float yv = 0.5f * (yf[(size_t)bl * 512 + t] + yb[(size_t)bl * 512 + t]) + Dp[h] * x;
    float z = zx[(size_t)bl * 1024 + t];
    float g = yv * (z / (1.f + expf(-z)));
    float v = g * g;
#pragma unroll
    for (int o = 32; o > 0; o >>= 1) v += __shfl_down(v, o, 64);
    __shared__ float rs[8];
    __shared__ float stot;
    if ((t & 63) == 0) rs[t >> 6] = v;
    __syncthreads();
    if (t == 0) {
        float s = 0.f;
#pragma unroll
        for (int i = 0; i < 8; i++) s += rs[i];
        stot = s;
    }
    __syncthreads();
    float rms = rsqrtf(stot / 512.f + 1e-5f);
    float kv = g * rms * knw[t];
    ushort_t hi, lo;
    bf16_split(kv, hi, lo);
    kh[(size_t)bl * 512 + t] = hi;
    kl[(size_t)bl * 512 + t] = lo;
}

// ---------------------------------------------------------------------------
// K5: layernorm on Savg rearranged to (B,Q,512); one block per (b,q).
// ---------------------------------------------------------------------------
__global__ __launch_bounds__(512) void k5_ln(const float* __restrict__ Savg,
                                             const float* __restrict__ lnw,
                                             const float* __restrict__ lnb,
                                             ushort_t* __restrict__ lh,
                                             ushort_t* __restrict__ ll) {
    int bq = blockIdx.x;
    int b = bq / QQ, q = bq % QQ;
    int t = threadIdx.x;
    int h = t >> 6, p = t & 63;
    float v = Savg[((b * 8 + h) * QP + q) * 64 + p];
    float s1 = v, s2 = v * v;
#pragma unroll
    for (int o = 32; o > 0; o >>= 1) {
        s1 += __shfl_down(s1, o, 64);
        s2 += __shfl_down(s2, o, 64);
    }
    __shared__ float r1[8], r2[8];
    __shared__ float smu, srv;
    if ((t & 63) == 0) { r1[t >> 6] = s1; r2[t >> 6] = s2; }
    __syncthreads();
    if (t == 0) {
        float a = 0.f, c = 0.f;
#pragma unroll
        for (int i = 0; i < 8; i++) { a += r1[i]; c += r2[i]; }
        float mu = a / 512.f;
        float var = c / 512.f - mu * mu;
        smu = mu;
        srv = rsqrtf(var + 1e-5f);
    }
    __syncthreads();
    float ov = (v - smu) * srv * lnw[t] + lnb[t];
    ushort_t hi, lo;
    bf16_split(ov, hi, lo);
    lh[(size_t)bq * 512 + t] = hi;
    ll[(size_t)bq * 512 + t] = lo;
}

// ---------------------------------------------------------------------------
extern "C" void kernel_launch(void* const* d_in, const int* in_sizes, int n_in,
                              void* d_out, int out_size, void* d_ws, size_t ws_size,
                              hipStream_t stream) {
    const float* in_key    = (const float*)d_in[0];
    const float* in_query  = (const float*)d_in[1];
    const float* dist      = (const float*)d_in[2];
    const float* W_key     = (const float*)d_in[3];
    const float* W_query   = (const float*)d_in[4];
    const float* W_bc      = (const float*)d_in[5];
    const float* W_dt      = (const float*)d_in[6];
    const float* dt_bias   = (const float*)d_in[7];
    const float* A_log     = (const float*)d_in[8];
    const float* Dp        = (const float*)d_in[9];
    const float* W_out_key = (const float*)d_in[10];
    const float* W_out_query = (const float*)d_in[11];
    const float* key_norm_w = (const float*)d_in[12];
    const float* ln_w      = (const float*)d_in[13];
    const float* ln_b      = (const float*)d_in[14];

    float* out_key = (float*)d_out;
    float* out_query = out_key + (size_t)BB * LL * D_MODEL;   // 2,097,152

    char* w8 = (char*)d_ws;
    auto alloc = [&](size_t bytes) {
        char* ptr = w8;
        w8 += (bytes + 255) & ~(size_t)255;
        return ptr;
    };
    float* zx     = (float*)alloc((size_t)8192 * 1024 * 4);
    float* bias10 = (float*)alloc((size_t)8192 * 10 * 4);
    float* S0q    = (float*)alloc((size_t)1200 * 512 * 4);
    float* dABb   = (float*)alloc((size_t)8192 * 8 * QP * 2 * 4);   // packed {dA,dtB}
    float* dAd    = (float*)alloc((size_t)8192 * 8 * QP * 4);       // dense dA (k2b/k3_corr)
    float* Cmb    = (float*)alloc((size_t)8192 * QP * 4);
    float* segd   = (float*)alloc((size_t)BB * NSEG * 8 * QP * 4);
    float* Sloc   = (float*)alloc((size_t)2 * NSEG * 32 * QP * 64 * 4);
    float* Sin    = (float*)alloc((size_t)2 * NSEG * 32 * QP * 64 * 4);
    float* yfb    = (float*)alloc((size_t)8192 * 512 * 4);
    float* ybb    = (float*)alloc((size_t)8192 * 512 * 4);
    float* Savg   = (float*)alloc((size_t)32 * QP * 64 * 4);
    ushort_t* ink_h  = (ushort_t*)alloc((size_t)2097152 * 2);
    ushort_t* ink_l  = (ushort_t*)alloc((size_t)2097152 * 2);
    ushort_t* wk_h   = (ushort_t*)alloc((size_t)262144 * 2);
    ushort_t* wk_l   = (ushort_t*)alloc((size_t)262144 * 2);
    ushort_t* inq_h  = (ushort_t*)alloc((size_t)307200 * 2);
    ushort_t* inq_l  = (ushort_t*)alloc((size_t)307200 * 2);
    ushort_t* wq_h   = (ushort_t*)alloc((size_t)131072 * 2);
    ushort_t* wq_l   = (ushort_t*)alloc((size_t)131072 * 2);
    ushort_t* keyb_h = (ushort_t*)alloc((size_t)4194304 * 2);
    ushort_t* keyb_l = (ushort_t*)alloc((size_t)4194304 * 2);
    ushort_t* wok_h  = (ushort_t*)alloc((size_t)131072 * 2);
    ushort_t* wok_l  = (ushort_t*)alloc((size_t)131072 * 2);
    ushort_t* lsn_h  = (ushort_t*)alloc((size_t)614400 * 2);
    ushort_t* lsn_l  = (ushort_t*)alloc((size_t)614400 * 2);
    ushort_t* woq_h  = (ushort_t*)alloc((size_t)131072 * 2);
    ushort_t* woq_l  = (ushort_t*)alloc((size_t)131072 * 2);

    // Input conversions (bf16 hi/lo)
    c_split<<<8192, 256, 0, stream>>>(in_key, ink_h, ink_l, 2097152);
    c_split<<<1024, 256, 0, stream>>>(W_key, wk_h, wk_l, 262144);       // rows 0..1023
    c_split<<<1200, 256, 0, stream>>>(in_query, inq_h, inq_l, 307200);
    c_split<<<512, 256, 0, stream>>>(W_query, wq_h, wq_l, 131072);
    c_split<<<512, 256, 0, stream>>>(W_out_key, wok_h, wok_l, 131072);
    c_split<<<512, 256, 0, stream>>>(W_out_query, woq_h, woq_l, 131072);

    // Projections
    gemm_bf16s<<<dim3(16, 64), 256, 0, stream>>>(ink_h, ink_l, wk_h, wk_l, zx, 8192, 1024, 256);
    k1b_bias<<<2048, 256, 0, stream>>>(in_key, W_key, bias10);
    gemm_bf16s<<<dim3(8, 10), 256, 0, stream>>>(inq_h, inq_l, wq_h, wq_l, S0q, 1200, 512, 256);

    // dist -> packed {dA,dtB} + dense dA + Cm
    k2_dist<<<9600, 256, 0, stream>>>(dist, bias10, W_bc, W_dt, dt_bias, A_log, dABb, dAd, Cmb);
    k2b_segdecay<<<640, 256, 0, stream>>>(dAd, segd);

    // segmented bidirectional scan: march + combine + MFMA correction
    pass_ac<<<dim3(NSEG, 32, 2), 256, 0, stream>>>(dABb, Cmb, zx, Sloc, yfb, ybb);
    pass_b<<<2560, 256, 0, stream>>>(Sloc, segd, S0q, Sin, Savg);
    k3_corr<<<dim3(NSEG, 32, 2), 256, 0, stream>>>(dAd, Cmb, Sin, yfb, ybb);

    // out_key path (k4 writes split-bf16 directly)
    k4_gate<<<8192, 512, 0, stream>>>(yfb, ybb, zx, Dp, key_norm_w, keyb_h, keyb_l);
    gemm_bf16s<<<dim3(4, 64), 256, 0, stream>>>(keyb_h, keyb_l, wok_h, wok_l, out_key, 8192, 256, 512);

    // out_query path (k5 writes split-bf16 directly)
    k5_ln<<<1200, 512, 0, stream>>>(Savg, ln_w, ln_b, lsn_h, lsn_l);
    gemm_bf16s<<<dim3(4, 10), 256, 0, stream>>>(lsn_h, lsn_l, woq_h, woq_l, out_query, 1200, 256, 512);
}

// Round 9
// 886.284 us; speedup vs baseline: 1.1031x; 1.0089x over previous
//
#include <hip/hip_runtime.h>
#include <hip/hip_bf16.h>

// Problem constants
#define D_MODEL 256
#define D_INNER 512
#define NHEADS 8
#define HEADDIM 64
#define MDIST 16
#define BB 4
#define LL 2048
#define QQ 300
#define QP 320          // padded Q
#define NSEG 16
#define SEGLEN 128      // LL / NSEG

typedef unsigned short ushort_t;
typedef __attribute__((ext_vector_type(8))) short bf16x8;
typedef __attribute__((ext_vector_type(4))) float f32x4;
typedef __attribute__((ext_vector_type(2))) float f32x2;

__device__ __forceinline__ void bf16_split(float v, ushort_t& hi, ushort_t& lo) {
    __hip_bfloat16 h = __float2bfloat16(v);
    float hf = __bfloat162float(h);
    __hip_bfloat16 l = __float2bfloat16(v - hf);
    hi = *(ushort_t*)&h;
    lo = *(ushort_t*)&l;
}

__device__ __forceinline__ f32x2 shfl_xor2(f32x2 v, int m) {
    f32x2 r;
    r.x = __shfl_xor(v.x, m, 64);
    r.y = __shfl_xor(v.y, m, 64);
    return r;
}

// DPP cross-lane move (VALU pipe, NOT the shared DS pipe).
// quad_perm 0xB1 = xor1, 0x4E = xor2, 0x128 = row_ror:8 (xor8 within row of 16).
template<int CTRL>
__device__ __forceinline__ f32x2 dpp2(f32x2 v) {
    f32x2 r;
    r.x = __int_as_float(__builtin_amdgcn_update_dpp(0, __float_as_int(v.x), CTRL, 0xF, 0xF, true));
    r.y = __int_as_float(__builtin_amdgcn_update_dpp(0, __float_as_int(v.y), CTRL, 0xF, 0xF, true));
    return r;
}
// ds_swizzle xor patterns: 0x101F = xor4, 0x401F = xor16
template<int OFF>
__device__ __forceinline__ f32x2 swz2(f32x2 v) {
    f32x2 r;
    r.x = __int_as_float(__builtin_amdgcn_ds_swizzle(__float_as_int(v.x), OFF));
    r.y = __int_as_float(__builtin_amdgcn_ds_swizzle(__float_as_int(v.y), OFF));
    return r;
}

// xor16 / xor32 reductions on the VALU pipe via gfx950 permlaneN_swap.
// With both operands equal, the two results are row-pairwise exchanges of q,
// so their SUM equals the xor-N reduction regardless of swap direction.
#if __has_builtin(__builtin_amdgcn_permlane16_swap)
__device__ __forceinline__ float red16_1(float v) {
    auto p = __builtin_amdgcn_permlane16_swap(__float_as_uint(v), __float_as_uint(v), false, false);
    return __uint_as_float(p[0]) + __uint_as_float(p[1]);
}
__device__ __forceinline__ f32x2 red16(f32x2 v) {
    f32x2 r; r.x = red16_1(v.x); r.y = red16_1(v.y); return r;
}
#else
__device__ __forceinline__ f32x2 red16(f32x2 v) { return v + swz2<0x401F>(v); }
#endif
#if __has_builtin(__builtin_amdgcn_permlane32_swap)
__device__ __forceinline__ float red32_1(float v) {
    auto p = __builtin_amdgcn_permlane32_swap(__float_as_uint(v), __float_as_uint(v), false, false);
    return __uint_as_float(p[0]) + __uint_as_float(p[1]);
}
__device__ __forceinline__ f32x2 red32(f32x2 v) {
    f32x2 r; r.x = red32_1(v.x); r.y = red32_1(v.y); return r;
}
#else
__device__ __forceinline__ f32x2 red32(f32x2 v) { return v + shfl_xor2(v, 32); }
#endif

// ---------------------------------------------------------------------------
// c_split6: batched split fp32 -> bf16 hi + lo for all six input arrays in a
// single launch (region sizes are exact multiples of 256 -> no tail checks).
// C = Ah*Bh + Ah*Bl + Al*Bh gives ~fp32 accuracy.
// ---------------------------------------------------------------------------
__global__ __launch_bounds__(256) void c_split6(
    const float* __restrict__ i0, ushort_t* __restrict__ h0, ushort_t* __restrict__ l0,  // in_key  8192 blk
    const float* __restrict__ i1, ushort_t* __restrict__ h1, ushort_t* __restrict__ l1,  // W_key   1024 blk
    const float* __restrict__ i2, ushort_t* __restrict__ h2, ushort_t* __restrict__ l2,  // in_q    1200 blk
    const float* __restrict__ i3, ushort_t* __restrict__ h3, ushort_t* __restrict__ l3,  // W_q      512 blk
    const float* __restrict__ i4, ushort_t* __restrict__ h4, ushort_t* __restrict__ l4,  // W_ok     512 blk
    const float* __restrict__ i5, ushort_t* __restrict__ h5, ushort_t* __restrict__ l5)  // W_oq     512 blk
{
    int blk = blockIdx.x;
    const float* in; ushort_t* hi; ushort_t* lo; int base;
    if (blk < 8192)       { in = i0; hi = h0; lo = l0; base = blk; }
    else if (blk < 9216)  { in = i1; hi = h1; lo = l1; base = blk - 8192; }
    else if (blk < 10416) { in = i2; hi = h2; lo = l2; base = blk - 9216; }
    else if (blk < 10928) { in = i3; hi = h3; lo = l3; base = blk - 10416; }
    else if (blk < 11440) { in = i4; hi = h4; lo = l4; base = blk - 10928; }
    else                  { in = i5; hi = h5; lo = l5; base = blk - 11440; }
    int i = base * 256 + threadIdx.x;
    ushort_t h, l;
    bf16_split(in[i], h, l);
    hi[i] = h;
    lo[i] = l;
}

// ---------------------------------------------------------------------------
// Split-bf16 MFMA GEMM: C[M,N] = A[M,K] * B[N,K]^T (NT), fp32 out.
// ---------------------------------------------------------------------------
__global__ __launch_bounds__(256) void gemm_bf16s(const ushort_t* __restrict__ Ah,
                                                  const ushort_t* __restrict__ Al,
                                                  const ushort_t* __restrict__ Bh,
                                                  const ushort_t* __restrict__ Bl,
                                                  float* __restrict__ C,
                                                  int M, int N, int K) {
    int w = threadIdx.x >> 6, lane = threadIdx.x & 63;
    int n0 = blockIdx.x * 64;
    int m0 = blockIdx.y * 128 + w * 32;
    int lm = lane & 15, lk = (lane >> 4) * 8;
    f32x4 acc[2][4];
#pragma unroll
    for (int i = 0; i < 2; i++)
#pragma unroll
        for (int j = 0; j < 4; j++) acc[i][j] = {0.f, 0.f, 0.f, 0.f};

    for (int k0 = 0; k0 < K; k0 += 32) {
        bf16x8 ah[2], al[2], bh[4], blo[4];
#pragma unroll
        for (int mf = 0; mf < 2; mf++) {
            int row = m0 + mf * 16 + lm;
            if (row >= M) row = M - 1;            // safe clamp; epilogue guards
            size_t off = (size_t)row * K + k0 + lk;
            ah[mf] = *(const bf16x8*)(Ah + off);
            al[mf] = *(const bf16x8*)(Al + off);
        }
#pragma unroll
        for (int nf = 0; nf < 4; nf++) {
            int col = n0 + nf * 16 + lm;
            size_t off = (size_t)col * K + k0 + lk;
            bh[nf]  = *(const bf16x8*)(Bh + off);
            blo[nf] = *(const bf16x8*)(Bl + off);
        }
#pragma unroll
        for (int mf = 0; mf < 2; mf++)
#pragma unroll
            for (int nf = 0; nf < 4; nf++) {
                acc[mf][nf] = __builtin_amdgcn_mfma_f32_16x16x32_bf16(ah[mf], bh[nf],  acc[mf][nf], 0, 0, 0);
                acc[mf][nf] = __builtin_amdgcn_mfma_f32_16x16x32_bf16(ah[mf], blo[nf], acc[mf][nf], 0, 0, 0);
                acc[mf][nf] = __builtin_amdgcn_mfma_f32_16x16x32_bf16(al[mf], bh[nf],  acc[mf][nf], 0, 0, 0);
            }
    }
#pragma unroll
    for (int mf = 0; mf < 2; mf++)
#pragma unroll
        for (int nf = 0; nf < 4; nf++)
#pragma unroll
            for (int r = 0; r < 4; r++) {
                int m = m0 + mf * 16 + (lane >> 4) * 4 + r;
                if (m < M) C[(size_t)m * N + n0 + nf * 16 + lm] = acc[mf][nf][r];
            }
}

// ---------------------------------------------------------------------------
// K1b: fp32 bias columns (rows 1024..1033 of W_key) — precision-critical.
// ---------------------------------------------------------------------------
__global__ __launch_bounds__(256) void k1b_bias(const float* __restrict__ in_key,
                                                const float* __restrict__ W_key,
                                                float* __restrict__ bias10) {
    int w = threadIdx.x >> 6, lane = threadIdx.x & 63;
    int row = blockIdx.x * 4 + w;
    float4 a = *(const float4*)(in_key + (size_t)row * 256 + lane * 4);
#pragma unroll
    for (int c = 0; c < 10; c++) {
        float4 b = *(const float4*)(W_key + (size_t)(1024 + c) * 256 + lane * 4);
        float t = a.x * b.x + a.y * b.y + a.z * b.z + a.w * b.w;
#pragma unroll
        for (int o = 32; o > 0; o >>= 1) t += __shfl_down(t, o, 64);
        if (lane == 0) bias10[row * 10 + c] = t;
    }
}

// ---------------------------------------------------------------------------
// K2: dist (B,L,Q,16) -> dAB packed (pass_ac staging), dAd dense (k2b +
// k3_corr full-sweep reads), Cm (B,L,QP). Now covers the FULL q in [0,QP)
// range: q in [QQ,QP) writes zeros so the padding region of dAB/dAd/Cm is
// defined (previously uninitialized workspace — latent re-poison hazard).
// ---------------------------------------------------------------------------
__global__ __launch_bounds__(256) void k2_dist(const float* __restrict__ dist,
                                               const float* __restrict__ bias10,
                                               const float* __restrict__ W_bc,
                                               const float* __restrict__ W_dt,
                                               const float* __restrict__ dt_bias,
                                               const float* __restrict__ A_log,
                                               float* __restrict__ dAB,
                                               float* __restrict__ dAd,
                                               float* __restrict__ Cm) {
    __shared__ float sWbc[32], sWdt[128], sb[8], sA[8];
    int tid = threadIdx.x;
    if (tid < 32) sWbc[tid] = W_bc[tid];
    else if (tid < 160) sWdt[tid - 32] = W_dt[tid - 32];
    else if (tid < 168) sb[tid - 160] = dt_bias[tid - 160];
    else if (tid < 176) sA[tid - 168] = -expf(A_log[tid - 168]);
    __syncthreads();
    int gid = blockIdx.x * 256 + tid;          // (b*L + l)*QP + q
    if (gid >= BB * LL * QP) return;
    int q = gid % QP;
    int bl = gid / QP;
    if (q >= QQ) {
        Cm[bl * QP + q] = 0.f;
#pragma unroll
        for (int h = 0; h < 8; h++) {
            int o = (bl * 8 + h) * QP + q;
            *(float2*)(dAB + (size_t)o * 2) = make_float2(0.f, 0.f);
            dAd[o] = 0.f;
        }
        return;
    }
    const float* dp = dist + (size_t)(bl * QQ + q) * 16;
    float d[16];
    float4 d0 = *(const float4*)(dp + 0);
    float4 d1 = *(const float4*)(dp + 4);
    float4 d2 = *(const float4*)(dp + 8);
    float4 d3 = *(const float4*)(dp + 12);
    d[0]=d0.x; d[1]=d0.y; d[2]=d0.z; d[3]=d0.w;
    d[4]=d1.x; d[5]=d1.y; d[6]=d1.z; d[7]=d1.w;
    d[8]=d2.x; d[9]=d2.y; d[10]=d2.z; d[11]=d2.w;
    d[12]=d3.x; d[13]=d3.y; d[14]=d3.z; d[15]=d3.w;
    float bc0 = 0.f, bc1 = 0.f;
#pragma unroll
    for (int m = 0; m < 16; m++) {
        bc0 = fmaf(d[m], sWbc[m], bc0);
        bc1 = fmaf(d[m], sWbc[16 + m], bc1);
    }
    float Bmv = bc0 + bias10[bl * 10 + 0];
    float Cv  = bc1 + bias10[bl * 10 + 1];
    Cm[bl * QP + q] = Cv;
#pragma unroll
    for (int h = 0; h < 8; h++) {
        float t = 0.f;
#pragma unroll
        for (int m = 0; m < 16; m++) t = fmaf(d[m], sWdt[h * 16 + m], t);
        float pre = t + bias10[bl * 10 + 2 + h] + sb[h];
        float dt = (pre > 20.f) ? pre : log1pf(expf(pre));
        int o = (bl * 8 + h) * QP + q;
        float2 v;
        v.x = expf(sA[h] * dt);      // dA
        v.y = dt * Bmv;              // dtB
        *(float2*)(dAB + (size_t)o * 2) = v;
        dAd[o] = v.x;
    }
}

// ---------------------------------------------------------------------------
// K2b: per-segment decay product segd (B,NSEG,H,QP). Reads DENSE dAd
// (stride-1 across lanes per iteration; ~84 MB total -> BW-bound ~15-25 µs).
// Standalone: fusing this product into pass_ac cost +16 VGPR / +56 µs (R7).
// ---------------------------------------------------------------------------
__global__ __launch_bounds__(256) void k2b_segdecay(const float* __restrict__ dA,
                                                    float* __restrict__ segd) {
    int gid = blockIdx.x * 256 + threadIdx.x;   // ((b*16+s)*8+h)*QP+q
    if (gid >= BB * NSEG * 8 * QP) return;
    int q = gid % QP; int r = gid / QP;
    int h = r % 8; r /= 8;
    int s = r % NSEG; int b = r / NSEG;
    size_t base = (size_t)((b * LL + s * SEGLEN) * 8 + h) * QP + q;
    float p = 1.f;
    for (int i = 0; i < SEGLEN; i++) p *= dA[base + (size_t)i * 8 * QP];
    segd[gid] = p;
}

// ---------------------------------------------------------------------------
// Pass AC (R4-measured body: 326 µs, VGPR 84, Occ 26%):
// segment-local march (S_in = 0), computes S_local AND y^loc.
// grid (NSEG, 32, 2), block 256 = 4 waves; wave w owns p in [16w, 16w+16),
// lane owns n in {64k+lane, k=0..4} -> S2[40] f32x2.
// G=4 LDS staging (32 KB, double-buffered), barrier per 4 steps.
// y-reduction: DPP quad_perm/row_ror + (R9) permlane16/32_swap on the VALU
// pipe; only the xor4 ds_swizzle remains on the DS pipe (DS ops/wave-step
// 20 -> 16). NO prodA fusion (R7: +16 VGPR, +56 µs) and NO inline-asm pk
// (R6: +28 VGPR, +65 µs) — both measured regressions on this body.
// ---------------------------------------------------------------------------
__global__ __launch_bounds__(256) void pass_ac(const float* __restrict__ dAB,
                                               const float* __restrict__ Cm,
                                               const float* __restrict__ zx,
                                               float* __restrict__ S_local,
                                               float* __restrict__ yf,
                                               float* __restrict__ yb) {
    __shared__ __align__(16) float sOp[2][4096];   // 32 KB: 4 steps x [ab 640 | c 320 | x 64]
    int seg = blockIdx.x, bh = blockIdx.y, dir = blockIdx.z;
    int tid = threadIdx.x;
    int w = tid >> 6, lane = tid & 63;
    int p0 = w * 16;
    int b = bh >> 3, h = bh & 7;
    f32x2 S2[40];                    // S2[k*8+j] <-> (n = 64k+lane, p = p0+2j+{0,1})
#pragma unroll
    for (int j = 0; j < 40; j++) S2[j] = {0.f, 0.f};
    float* __restrict__ yo = dir ? yb : yf;
    bool s1 = (lane & 1) != 0, s2b = (lane & 2) != 0, s4 = (lane & 4) != 0;

    int pos = tid * 4;               // this thread's 4-float slice of each step
    auto stage = [&](int g, int buf) {
#pragma unroll
        for (int r = 0; r < 4; r++) {
            int i = g * 4 + r;
            int l = dir ? (LL - 1 - (seg * SEGLEN + i)) : (seg * SEGLEN + i);
            int bl = b * LL + l;
            const float* src;
            if (pos < 640)      src = dAB + (size_t)(bl * 8 + h) * 640 + pos;
            else if (pos < 960) src = Cm + (size_t)bl * QP + (pos - 640);
            else                src = zx + (size_t)bl * 1024 + 512 + h * 64 + (pos - 960);
            *(float4*)&sOp[buf][r * 1024 + pos] = *(const float4*)src;
        }
    };
    stage(0, 0);
    const int NGRP = SEGLEN / 4;          // 32 groups of 4 steps
    for (int g = 0; g < NGRP; g++) {
        __syncthreads();
        if (g + 1 < NGRP) stage(g + 1, (g + 1) & 1);
        const float* bufg = &sOp[g & 1][0];
#pragma unroll
        for (int it = 0; it < 4; it++) {
            const float* Bq = bufg + it * 1024;
            // x: wave-uniform 16 floats (broadcast b128 reads)
            float4 xq0 = *(const float4*)(Bq + 960 + p0);
            float4 xq1 = *(const float4*)(Bq + 964 + p0);
            float4 xq2 = *(const float4*)(Bq + 968 + p0);
            float4 xq3 = *(const float4*)(Bq + 972 + p0);
            f32x2 x2[8] = {{xq0.x, xq0.y}, {xq0.z, xq0.w}, {xq1.x, xq1.y}, {xq1.z, xq1.w},
                           {xq2.x, xq2.y}, {xq2.z, xq2.w}, {xq3.x, xq3.y}, {xq3.z, xq3.w}};
            f32x2 y[8];
#pragma unroll
            for (int j = 0; j < 8; j++) y[j] = {0.f, 0.f};
#pragma unroll
            for (int k = 0; k < 5; k++) {
                int n = k * 64 + lane;
                f32x2 ab = *(const f32x2*)(Bq + 2 * n);     // {dA, dtB}, b64 unique
                float c = Bq[640 + n];                      // b32 unique
                f32x2 a2 = {ab.x, ab.x}, b2 = {ab.y, ab.y}, c2 = {c, c};
#pragma unroll
                for (int j = 0; j < 8; j++) {
                    f32x2 s = S2[k * 8 + j] * a2 + b2 * x2[j];
                    S2[k * 8 + j] = s;
                    y[j] += s * c2;
                }
            }
            // reduce-scatter 8 items over 64 lanes; final item (lane&7)
            // L1/L2: DPP quad_perm (VALU); L4: ds_swizzle; L8: DPP ror;
            // L16/L32: permlane16/32_swap (VALU — was swizzle+shfl on DS).
            f32x2 u, v, z0, z1, z2, z3, w0, w1, q;
            u = s1 ? y[1] : y[0]; v = s1 ? y[0] : y[1]; z0 = u + dpp2<0xB1>(v);
            u = s1 ? y[3] : y[2]; v = s1 ? y[2] : y[3]; z1 = u + dpp2<0xB1>(v);
            u = s1 ? y[5] : y[4]; v = s1 ? y[4] : y[5]; z2 = u + dpp2<0xB1>(v);
            u = s1 ? y[7] : y[6]; v = s1 ? y[6] : y[7]; z3 = u + dpp2<0xB1>(v);
            u = s2b ? z1 : z0; v = s2b ? z0 : z1; w0 = u + dpp2<0x4E>(v);
            u = s2b ? z3 : z2; v = s2b ? z2 : z3; w1 = u + dpp2<0x4E>(v);
            u = s4 ? w1 : w0; v = s4 ? w0 : w1; q = u + swz2<0x101F>(v);
            q = q + dpp2<0x128>(q);       // xor8 (row_ror:8)
            q = red16(q);                 // xor16 (permlane16_swap, VALU)
            q = red32(q);                 // xor32 (permlane32_swap, VALU)
            if (lane < 8) {
                int i = g * 4 + it;
                int l = dir ? (LL - 1 - (seg * SEGLEN + i)) : (seg * SEGLEN + i);
                int bl = b * LL + l;
                *(f32x2*)(yo + (size_t)(bl * 8 + h) * 64 + p0 + 2 * lane) = q;
            }
        }
    }
    // epilogue: store S_local (lane's 5 n-rows, 16 p's each)
    size_t base = (size_t)((dir * NSEG + seg) * 32 + bh) * QP * 64;
#pragma unroll
    for (int k = 0; k < 5; k++) {
        int n = k * 64 + lane;
#pragma unroll
        for (int t = 0; t < 4; t++) {
            float4 vv = {S2[k * 8 + 2 * t].x, S2[k * 8 + 2 * t].y,
                         S2[k * 8 + 2 * t + 1].x, S2[k * 8 + 2 * t + 1].y};
            *(float4*)&S_local[base + (size_t)n * 64 + p0 + 4 * t] = vv;
        }
    }
}

// ---------------------------------------------------------------------------
// Pass B: sequential segment combine (16 steps), writes S_in per segment and
// the averaged final state Savg (B,H,QP,P)
// ---------------------------------------------------------------------------
__global__ __launch_bounds__(256) void pass_b(const float* __restrict__ S_local,
                                              const float* __restrict__ segd,
                                              const float* __restrict__ S0q,
                                              float* __restrict__ S_in,
                                              float* __restrict__ Savg) {
    int gid = blockIdx.x * 256 + threadIdx.x;   // (b,h,n,p)
    if (gid >= BB * 8 * QP * 64) return;
    int p = gid & 63; int r = gid >> 6;
    int n = r % QP; r /= QP;
    int h = r & 7; int b = r >> 3;
    int bh = b * 8 + h;
    float s0 = (n < QQ) ? S0q[(size_t)(b * QQ + n) * 512 + h * 64 + p] : 0.f;
    float Sf = 0.f, Sb = 0.f;
    for (int dir = 0; dir < 2; dir++) {
        float S = s0;
        for (int s = 0; s < NSEG; s++) {
            size_t idx = (size_t)(((dir * NSEG + s) * 32 + bh) * QP + n) * 64 + p;
            S_in[idx] = S;
            int sf = dir ? (NSEG - 1 - s) : s;
            float dec = segd[((b * NSEG + sf) * 8 + h) * QP + n];
            S = fmaf(S, dec, S_local[idx]);
        }
        if (dir == 0) Sf = S; else Sb = S;
    }
    Savg[((bh) * QP + n) * 64 + p] = 0.5f * (Sf + Sb);
}

// ---------------------------------------------------------------------------
// K3_corr: y += Ahat @ S_in per (seg,bh,dir), where Ahat[i,n] = C_i[n] *
// cumprod_{k<=i} dA_k[n]. M=128 (steps), K=320 (n), N=64 (p).
// Reads the DENSE dA copy (dAd) — stride-1, no packed-layout amplification.
// ---------------------------------------------------------------------------
__global__ __launch_bounds__(256) void k3_corr(const float* __restrict__ dA,
                                               const float* __restrict__ Cm,
                                               const float* __restrict__ Sin,
                                               float* __restrict__ yf,
                                               float* __restrict__ yb) {
    __shared__ __align__(16) ushort_t sAh[128][48], sAl[128][48];  // 12 KB each
    __shared__ __align__(16) ushort_t sBh[64][48], sBl[64][48];    // 6 KB each
    __shared__ float pref[8][32];
    int seg = blockIdx.x, bh = blockIdx.y, dir = blockIdx.z;
    int b = bh >> 3, h = bh & 7;
    int tid = threadIdx.x;
    int w = tid >> 6, lane = tid & 63;
    int lm = lane & 15, lkq = lane >> 4;
    f32x4 acc[2][4];
#pragma unroll
    for (int i = 0; i < 2; i++)
#pragma unroll
        for (int j = 0; j < 4; j++) acc[i][j] = {0.f, 0.f, 0.f, 0.f};
    size_t sinBase = (size_t)((dir * NSEG + seg) * 32 + bh) * QP * 64;
    int nl = tid & 31, iseg = tid >> 5;   // cumprod roles: 32 n x 8 i-segments

    for (int k0 = 0; k0 < QP; k0 += 32) {
        __syncthreads();   // protect LDS reuse across chunks
        // ---- stage S_in chunk -> sB [p][k] split-bf16 ----
#pragma unroll
        for (int r = 0; r < 8; r++) {
            int flat = tid + r * 256;          // 0..2047
            int kn = flat >> 6, p = flat & 63;
            float v = Sin[sinBase + (size_t)(k0 + kn) * 64 + p];
            ushort_t hi, lo;
            bf16_split(v, hi, lo);
            sBh[p][kn] = hi;
            sBl[p][kn] = lo;
        }
        // ---- load dA/Cm for 16-step chain, local product ----
        float da[16], cm[16];
#pragma unroll
        for (int k = 0; k < 16; k++) {
            int i = iseg * 16 + k;
            int l = dir ? (LL - 1 - (seg * SEGLEN + i)) : (seg * SEGLEN + i);
            int bl = b * LL + l;
            da[k] = dA[(size_t)(bl * 8 + h) * QP + k0 + nl];
            cm[k] = Cm[(size_t)bl * QP + k0 + nl];
        }
        float lp = 1.f;
#pragma unroll
        for (int k = 0; k < 16; k++) lp *= da[k];
        pref[iseg][nl] = lp;
        __syncthreads();
        if (tid < 32) {                       // exclusive prefix over i-segments
            float c = 1.f;
#pragma unroll
            for (int s = 0; s < 8; s++) {
                float t = pref[s][tid];
                pref[s][tid] = c;
                c *= t;
            }
        }
        __syncthreads();
        float cum = pref[iseg][nl];
#pragma unroll
        for (int k = 0; k < 16; k++) {
            cum *= da[k];
            float v = cum * cm[k];
            ushort_t hi, lo;
            bf16_split(v, hi, lo);
            int i = iseg * 16 + k;
            sAh[i][nl] = hi;
            sAl[i][nl] = lo;
        }
        __syncthreads();
        // ---- MFMA ----
        bf16x8 ah[2], al[2], bhf[4], blf[4];
#pragma unroll
        for (int mf = 0; mf < 2; mf++) {
            int row = w * 32 + mf * 16 + lm;
            ah[mf] = *(const bf16x8*)&sAh[row][lkq * 8];
            al[mf] = *(const bf16x8*)&sAl[row][lkq * 8];
        }
#pragma unroll
        for (int nf = 0; nf < 4; nf++) {
            int p = nf * 16 + lm;
            bhf[nf] = *(const bf16x8*)&sBh[p][lkq * 8];
            blf[nf] = *(const bf16x8*)&sBl[p][lkq * 8];
        }
#pragma unroll
        for (int mf = 0; mf < 2; mf++)
#pragma unroll
            for (int nf = 0; nf < 4; nf++) {
                acc[mf][nf] = __builtin_amdgcn_mfma_f32_16x16x32_bf16(ah[mf], bhf[nf], acc[mf][nf], 0, 0, 0);
                acc[mf][nf] = __builtin_amdgcn_mfma_f32_16x16x32_bf16(ah[mf], blf[nf], acc[mf][nf], 0, 0, 0);
                acc[mf][nf] = __builtin_amdgcn_mfma_f32_16x16x32_bf16(al[mf], bhf[nf], acc[mf][nf], 0, 0, 0);
            }
    }
    // ---- epilogue: y += correction ----
    float* __restrict__ yo = dir ? yb : yf;
#pragma unroll
    for (int mf = 0; mf < 2; mf++)
#pragma unroll
        for (int nf = 0; nf < 4; nf++)
#pragma unroll
            for (int r = 0; r < 4; r++) {
                int i = w * 32 + mf * 16 + lkq * 4 + r;
                int p = nf * 16 + lm;
                int l = dir ? (LL - 1 - (seg * SEGLEN + i)) : (seg * SEGLEN + i);
                size_t idx = (size_t)((b * LL + l) * 8 + h) * 64 + p;
                yo[idx] += acc[mf][nf][r];
            }
}

// ---------------------------------------------------------------------------
// K4: y = 0.5*(yf+yb) + Dp*x ; g = y*silu(z) ; key = g * rms(g) * key_norm_w
// ---------------------------------------------------------------------------
__global__ __launch_bounds__(512) void k4_gate(const float* __restrict__ yf,
                                               const float* __restrict__ yb,
                                               const float* __restrict__ zx,
                                               const float* __restrict__ Dp,
                                               const float* __restrict__ knw,
                                               ushort_t* __restrict__ kh,
                                               ushort_t* __restrict__ kl) {
    int bl = blockIdx.x;
    int t = threadIdx.x;
    int h = t >> 6;
    float x = zx[(size_t)bl * 1024 + 512 + t];
    float yv = 0.5f * (yf[(size_t)bl * 512 + t] + yb[(size_t)bl * 512 + t]) + Dp[h] * x;
    float z = zx[(size_t)bl * 1024 + t];
    float g = yv * (z / (1.f + expf(-z)));
    float v = g * g;
#pragma unroll
    for (int o = 32; o > 0; o >>= 1) v += __shfl_down(v, o, 64);
    __shared__ float rs[8];
    __shared__ float stot;
    if ((t & 63) == 0) rs[t >> 6] = v;
    __syncthreads();
    if (t == 0) {
        float s = 0.f;
#pragma unroll
        for (int i = 0; i < 8; i++) s += rs[i];
        stot = s;
    }
    __syncthreads();
    float rms = rsqrtf(stot / 512.f + 1e-5f);
    float kv = g * rms * knw[t];
    ushort_t hi, lo;
    bf16_split(kv, hi, lo);
    kh[(size_t)bl * 512 + t] = hi;
    kl[(size_t)bl * 512 + t] = lo;
}

// ---------------------------------------------------------------------------
// K5: layernorm on Savg rearranged to (B,Q,512); one block per (b,q).
// ---------------------------------------------------------------------------
__global__ __launch_bounds__(512) void k5_ln(const float* __restrict__ Savg,
                                             const float* __restrict__ lnw,
                                             const float* __restrict__ lnb,
                                             ushort_t* __restrict__ lh,
                                             ushort_t* __restrict__ ll) {
    int bq = blockIdx.x;
    int b = bq / QQ, q = bq % QQ;
    int t = threadIdx.x;
    int h = t >> 6, p = t & 63;
    float v = Savg[((b * 8 + h) * QP + q) * 64 + p];
    float s1 = v, s2 = v * v;
#pragma unroll
    for (int o = 32; o > 0; o >>= 1) {
        s1 += __shfl_down(s1, o, 64);
        s2 += __shfl_down(s2, o, 64);
    }
    __shared__ float r1[8], r2[8];
    __shared__ float smu, srv;
    if ((t & 63) == 0) { r1[t >> 6] = s1; r2[t >> 6] = s2; }
    __syncthreads();
    if (t == 0) {
        float a = 0.f, c = 0.f;
#pragma unroll
        for (int i = 0; i < 8; i++) { a += r1[i]; c += r2[i]; }
        float mu = a / 512.f;
        float var = c / 512.f - mu * mu;
        smu = mu;
        srv = rsqrtf(var + 1e-5f);
    }
    __syncthreads();
    float ov = (v - smu) * srv * lnw[t] + lnb[t];
    ushort_t hi, lo;
    bf16_split(ov, hi, lo);
    lh[(size_t)bq * 512 + t] = hi;
    ll[(size_t)bq * 512 + t] = lo;
}

// ---------------------------------------------------------------------------
extern "C" void kernel_launch(void* const* d_in, const int* in_sizes, int n_in,
                              void* d_out, int out_size, void* d_ws, size_t ws_size,
                              hipStream_t stream) {
    const float* in_key    = (const float*)d_in[0];
    const float* in_query  = (const float*)d_in[1];
    const float* dist      = (const float*)d_in[2];
    const float* W_key     = (const float*)d_in[3];
    const float* W_query   = (const float*)d_in[4];
    const float* W_bc      = (const float*)d_in[5];
    const float* W_dt      = (const float*)d_in[6];
    const float* dt_bias   = (const float*)d_in[7];
    const float* A_log     = (const float*)d_in[8];
    const float* Dp        = (const float*)d_in[9];
    const float* W_out_key = (const float*)d_in[10];
    const float* W_out_query = (const float*)d_in[11];
    const float* key_norm_w = (const float*)d_in[12];
    const float* ln_w      = (const float*)d_in[13];
    const float* ln_b      = (const float*)d_in[14];

    float* out_key = (float*)d_out;
    float* out_query = out_key + (size_t)BB * LL * D_MODEL;   // 2,097,152

    char* w8 = (char*)d_ws;
    auto alloc = [&](size_t bytes) {
        char* ptr = w8;
        w8 += (bytes + 255) & ~(size_t)255;
        return ptr;
    };
    float* zx     = (float*)alloc((size_t)8192 * 1024 * 4);
    float* bias10 = (float*)alloc((size_t)8192 * 10 * 4);
    float* S0q    = (float*)alloc((size_t)1200 * 512 * 4);
    float* dABb   = (float*)alloc((size_t)8192 * 8 * QP * 2 * 4);   // packed {dA,dtB}
    float* dAd    = (float*)alloc((size_t)8192 * 8 * QP * 4);       // dense dA (k2b/k3_corr)
    float* Cmb    = (float*)alloc((size_t)8192 * QP * 4);
    float* segd   = (float*)alloc((size_t)BB * NSEG * 8 * QP * 4);
    float* Sloc   = (float*)alloc((size_t)2 * NSEG * 32 * QP * 64 * 4);
    float* Sin    = (float*)alloc((size_t)2 * NSEG * 32 * QP * 64 * 4);
    float* yfb    = (float*)alloc((size_t)8192 * 512 * 4);
    float* ybb    = (float*)alloc((size_t)8192 * 512 * 4);
    float* Savg   = (float*)alloc((size_t)32 * QP * 64 * 4);
    ushort_t* ink_h  = (ushort_t*)alloc((size_t)2097152 * 2);
    ushort_t* ink_l  = (ushort_t*)alloc((size_t)2097152 * 2);
    ushort_t* wk_h   = (ushort_t*)alloc((size_t)262144 * 2);
    ushort_t* wk_l   = (ushort_t*)alloc((size_t)262144 * 2);
    ushort_t* inq_h  = (ushort_t*)alloc((size_t)307200 * 2);
    ushort_t* inq_l  = (ushort_t*)alloc((size_t)307200 * 2);
    ushort_t* wq_h   = (ushort_t*)alloc((size_t)131072 * 2);
    ushort_t* wq_l   = (ushort_t*)alloc((size_t)131072 * 2);
    ushort_t* keyb_h = (ushort_t*)alloc((size_t)4194304 * 2);
    ushort_t* keyb_l = (ushort_t*)alloc((size_t)4194304 * 2);
    ushort_t* wok_h  = (ushort_t*)alloc((size_t)131072 * 2);
    ushort_t* wok_l  = (ushort_t*)alloc((size_t)131072 * 2);
    ushort_t* lsn_h  = (ushort_t*)alloc((size_t)614400 * 2);
    ushort_t* lsn_l  = (ushort_t*)alloc((size_t)614400 * 2);
    ushort_t* woq_h  = (ushort_t*)alloc((size_t)131072 * 2);
    ushort_t* woq_l  = (ushort_t*)alloc((size_t)131072 * 2);

    // Input conversions (bf16 hi/lo) — one batched launch, 11952 blocks
    c_split6<<<11952, 256, 0, stream>>>(in_key, ink_h, ink_l,
                                        W_key, wk_h, wk_l,
                                        in_query, inq_h, inq_l,
                                        W_query, wq_h, wq_l,
                                        W_out_key, wok_h, wok_l,
                                        W_out_query, woq_h, woq_l);

    // Projections
    gemm_bf16s<<<dim3(16, 64), 256, 0, stream>>>(ink_h, ink_l, wk_h, wk_l, zx, 8192, 1024, 256);
    k1b_bias<<<2048, 256, 0, stream>>>(in_key, W_key, bias10);
    gemm_bf16s<<<dim3(8, 10), 256, 0, stream>>>(inq_h, inq_l, wq_h, wq_l, S0q, 1200, 512, 256);

    // dist -> packed {dA,dtB} + dense dA + Cm (full QP range, zero padding)
    k2_dist<<<10240, 256, 0, stream>>>(dist, bias10, W_bc, W_dt, dt_bias, A_log, dABb, dAd, Cmb);
    k2b_segdecay<<<640, 256, 0, stream>>>(dAd, segd);

    // segmented bidirectional scan: march + combine + MFMA correction
    pass_ac<<<dim3(NSEG, 32, 2), 256, 0, stream>>>(dABb, Cmb, zx, Sloc, yfb, ybb);
    pass_b<<<2560, 256, 0, stream>>>(Sloc, segd, S0q, Sin, Savg);
    k3_corr<<<dim3(NSEG, 32, 2), 256, 0, stream>>>(dAd, Cmb, Sin, yfb, ybb);

    // out_key path (k4 writes split-bf16 directly)
    k4_gate<<<8192, 512, 0, stream>>>(yfb, ybb, zx, Dp, key_norm_w, keyb_h, keyb_l);
    gemm_bf16s<<<dim3(4, 64), 256, 0, stream>>>(keyb_h, keyb_l, wok_h, wok_l, out_key, 8192, 256, 512);

    // out_query path (k5 writes split-bf16 directly)
    k5_ln<<<1200, 512, 0, stream>>>(Savg, ln_w, ln_b, lsn_h, lsn_l);
    gemm_bf16s<<<dim3(4, 10), 256, 0, stream>>>(lsn_h, lsn_l, woq_h, woq_l, out_query, 1200, 256, 512);
}